// Round 4
// baseline (2320.772 us; speedup 1.0000x reference)
//
#include <hip/hip_runtime.h>

typedef _Float16 half_t;
typedef _Float16 half2_t __attribute__((ext_vector_type(2)));
typedef _Float16 half4_t __attribute__((ext_vector_type(4)));
typedef _Float16 half8_t __attribute__((ext_vector_type(8)));
typedef float float4_t __attribute__((ext_vector_type(4)));

// Problem constants
#define BB 64
#define TT 512
#define EE 128
#define HPP 128
#define KK 32
#define MTOT (BB*TT)     // 32768
#define NWID 1024        // stacked fwd(512)+bwd(512) gate rows, gate-interleaved per dir

// barrier that drains ONLY LDS ops (z prefetch + h global stores stay in flight)
__device__ __forceinline__ void lds_barrier() {
    asm volatile("s_waitcnt lgkmcnt(0)\n\ts_barrier" ::: "memory");
}

// ---------------------------------------------------------------- lengths
__global__ void k_lengths(const int* __restrict__ x, int* __restrict__ lens) {
    __shared__ int cnt;
    if (threadIdx.x == 0) cnt = 0;
    __syncthreads();
    int local = 0;
    for (int t = threadIdx.x; t < TT; t += blockDim.x)
        local += (x[blockIdx.x * TT + t] > 0) ? 1 : 0;
    atomicAdd(&cnt, local);
    __syncthreads();
    if (threadIdx.x == 0) lens[blockIdx.x] = cnt;
}

// ---------------------------------------------------------------- pack weights fp32->fp16 (wi stacked [fwd;bwd], [N,K]; w_out [32,256])
__global__ void k_pack(const float* __restrict__ wi0f, const float* __restrict__ wi0b,
                       const float* __restrict__ wi1f, const float* __restrict__ wi1b,
                       const float* __restrict__ w_out,
                       half_t* __restrict__ W0, half_t* __restrict__ W1,
                       half_t* __restrict__ WO) {
    int idx = blockIdx.x * blockDim.x + threadIdx.x;
    int stride = gridDim.x * blockDim.x;
    const int n0 = NWID * EE;
    const int n1 = NWID * 256;
    for (int i = idx; i < n0; i += stride) {
        int r = i >> 7, c = i & 127;
        float v = (r < 512) ? wi0f[r * 128 + c] : wi0b[(r - 512) * 128 + c];
        W0[i] = (half_t)v;
    }
    for (int i = idx; i < n1; i += stride) {
        int r = i >> 8, c = i & 255;
        float v = (r < 512) ? wi1f[r * 256 + c] : wi1b[(r - 512) * 256 + c];
        W1[i] = (half_t)v;
    }
    for (int i = idx; i < KK * 256; i += stride)
        WO[i] = (half_t)w_out[i];
}

// ---------------------------------------------------------------- embedding gather -> fp16
__global__ void k_embed(const int* __restrict__ x, const float* __restrict__ embed,
                        half_t* __restrict__ e16) {
    int bt = blockIdx.x * 16 + (threadIdx.x >> 4);
    int c  = (threadIdx.x & 15) * 8;
    int xi = x[bt];
    const float4* src = (const float4*)(embed + (size_t)xi * EE + c);
    float4 a = src[0], b = src[1];
    half8_t o;
    o[0] = (half_t)a.x; o[1] = (half_t)a.y; o[2] = (half_t)a.z; o[3] = (half_t)a.w;
    o[4] = (half_t)b.x; o[5] = (half_t)b.y; o[6] = (half_t)b.z; o[7] = (half_t)b.w;
    *(half8_t*)(e16 + (size_t)bt * EE + c) = o;
}

// ---------------------------------------------------------------- MFMA GEMM: C[M,1024] = A[M,Kd]*W[1024,Kd]^T + bias
// epilogue permutes n -> gate-interleaved: within each dir-half, np = cell*4 + gate
__global__ __launch_bounds__(256) void k_gemm(const half_t* __restrict__ A,
                                              const half_t* __restrict__ W,
                                              const float* __restrict__ bias_f,
                                              const float* __restrict__ bias_b,
                                              half_t* __restrict__ C, int Kd) {
    int wave = threadIdx.x >> 6;
    int lane = threadIdx.x & 63;
    int m0 = blockIdx.x * 64 + wave * 16;
    int n0 = blockIdx.y * 256;
    int lr = lane & 15;
    int lq = lane >> 4;

    float4_t acc[16];
    #pragma unroll
    for (int i = 0; i < 16; i++) acc[i] = (float4_t){0.f, 0.f, 0.f, 0.f};

    const half_t* Arow = A + (size_t)(m0 + lr) * Kd + lq * 8;
    const half_t* Wrow = W + (size_t)(n0 + lr) * Kd + lq * 8;

    for (int k = 0; k < Kd; k += 32) {
        half8_t af = *(const half8_t*)(Arow + k);
        #pragma unroll
        for (int nt = 0; nt < 16; nt++) {
            half8_t bf = *(const half8_t*)(Wrow + (size_t)nt * 16 * Kd + k);
            acc[nt] = __builtin_amdgcn_mfma_f32_16x16x32_f16(af, bf, acc[nt], 0, 0, 0);
        }
    }
    #pragma unroll
    for (int nt = 0; nt < 16; nt++) {
        int n = n0 + nt * 16 + lr;
        int n2 = (n < 512) ? n : n - 512;
        float bias = (n < 512) ? bias_f[n2] : bias_b[n2];
        int np = ((n < 512) ? 0 : 512) + (n2 & 127) * 4 + (n2 >> 7);
        #pragma unroll
        for (int i = 0; i < 4; i++) {
            int m = m0 + lq * 4 + i;
            C[(size_t)m * NWID + np] = (half_t)(acc[nt][i] + bias);
        }
    }
}

// ---------------------------------------------------------------- recurrent LSTM via MFMA, 16 chains per block
// grid = 8 blocks (4 seq-groups x 2 dirs), 512 thr (8 waves).
// Per step: gates[512,16] = Wh[512,128] (A, regs) x h[128,16] (B, LDS) ; 16 MFMA/wave.
// Gate-interleaved rows => lane (quad,n) holds all 4 gates of cell (mt*4+quad), seq n in acc regs.
__global__ __launch_bounds__(512, 1) void k_lstm(const half_t* __restrict__ zbuf,
                                                 const float* __restrict__ wh_f,
                                                 const float* __restrict__ wh_b,
                                                 const int* __restrict__ lens,
                                                 half_t* __restrict__ hout) {
    const int bgrp = blockIdx.x >> 1;
    const int dir  = blockIdx.x & 1;
    const int tid  = threadIdx.x;
    const int wv   = tid >> 6;
    const int lane = tid & 63;
    const int n    = lane & 15;       // seq within group (B col); also A-row within tile
    const int quad = lane >> 4;       // k-quad
    const int b    = bgrp * 16 + n;
    const int Lb   = lens[b];
    const int maxL = lens[bgrp * 16];   // lengths sorted descending
    const float* wh = dir ? wh_b : wh_f;

    __shared__ half_t hb[2][2048];   // [buf][kblk 16][seq 16][kin 8]

    // ---- A fragments (weights): 4 Mtiles x 4 Ktiles x 8 halfs = 64 regs (AGPR-friendly)
    half8_t a[4][4];
    #pragma unroll
    for (int i = 0; i < 4; i++) {
        int mt = wv * 4 + i;
        int r = mt * 16 + n;                  // interleaved row = cell*4+gate
        int orow = (r & 3) * 128 + (r >> 2);  // original wh row = gate*128+cell
        #pragma unroll
        for (int kt = 0; kt < 4; kt++) {
            const float4* src = (const float4*)(wh + (size_t)orow * 128 + kt * 32 + quad * 8);
            float4 f0 = src[0], f1 = src[1];
            half8_t h8;
            h8[0] = (half_t)f0.x; h8[1] = (half_t)f0.y; h8[2] = (half_t)f0.z; h8[3] = (half_t)f0.w;
            h8[4] = (half_t)f1.x; h8[5] = (half_t)f1.y; h8[6] = (half_t)f1.z; h8[7] = (half_t)f1.w;
            a[i][kt] = h8;
        }
    }

    // zero h(0) buffer
    for (int i = tid; i < 2048; i += 512) hb[0][i] = (half_t)0.f;

    // per-lane constants
    int rd[4];
    #pragma unroll
    for (int kt = 0; kt < 4; kt++) rd[kt] = (kt * 4 + quad) * 128 + n * 8;
    int cellv[4], wrv[4];
    #pragma unroll
    for (int i = 0; i < 4; i++) {
        cellv[i] = wv * 16 + i * 4 + quad;
        wrv[i] = (cellv[i] >> 3) * 128 + n * 8 + (cellv[i] & 7);
    }
    float c[4] = {0.f, 0.f, 0.f, 0.f};

    const half_t* zb = zbuf + dir * 512;
    half_t* hob = hout + dir * 128;

    // z prefetch ring, depth 2 (one half4 = 4 gates per unit)
    half4_t z1[4], z2[4];
    {
        int t0 = dir ? (Lb - 1) : 0;
        int t1 = dir ? (Lb - 2) : 1;       // Lb >= 256
        const half_t* p0 = zb + (size_t)(b * TT + t0) * NWID;
        const half_t* p1 = zb + (size_t)(b * TT + t1) * NWID;
        #pragma unroll
        for (int i = 0; i < 4; i++) {
            z1[i] = *(const half4_t*)(p0 + cellv[i] * 4);
            z2[i] = *(const half4_t*)(p1 + cellv[i] * 4);
        }
    }
    __syncthreads();

    for (int t = 0; t < maxL; t++) {
        const int rb = t & 1;

        half8_t bf0 = *(const half8_t*)&hb[rb][rd[0]];
        half8_t bf1 = *(const half8_t*)&hb[rb][rd[1]];
        half8_t bf2 = *(const half8_t*)&hb[rb][rd[2]];
        half8_t bf3 = *(const half8_t*)&hb[rb][rd[3]];

        float4_t acc[4];
        #pragma unroll
        for (int i = 0; i < 4; i++) acc[i] = (float4_t){0.f, 0.f, 0.f, 0.f};
        #pragma unroll
        for (int i = 0; i < 4; i++) {
            acc[i] = __builtin_amdgcn_mfma_f32_16x16x32_f16(a[i][0], bf0, acc[i], 0, 0, 0);
            acc[i] = __builtin_amdgcn_mfma_f32_16x16x32_f16(a[i][1], bf1, acc[i], 0, 0, 0);
            acc[i] = __builtin_amdgcn_mfma_f32_16x16x32_f16(a[i][2], bf2, acc[i], 0, 0, 0);
            acc[i] = __builtin_amdgcn_mfma_f32_16x16x32_f16(a[i][3], bf3, acc[i], 0, 0, 0);
        }

        // prefetch z(t+2)
        half4_t zn[4];
        {
            int tp = t + 2;
            int tn = dir ? (Lb - 1 - tp) : tp;
            tn = tn < 0 ? 0 : (tn > TT - 1 ? TT - 1 : tn);
            const half_t* p = zb + (size_t)(b * TT + tn) * NWID;
            #pragma unroll
            for (int i = 0; i < 4; i++) zn[i] = *(const half4_t*)(p + cellv[i] * 4);
        }

        int tcur = dir ? (Lb - 1 - t) : t;
        bool valid = (t < Lb);
        size_t gbase = (size_t)(b * TT + (tcur < 0 ? 0 : tcur)) * 256;

        #pragma unroll
        for (int i = 0; i < 4; i++) {
            float zi = acc[i][0] + (float)z1[i][0];
            float zf = acc[i][1] + (float)z1[i][1];
            float zg = acc[i][2] + (float)z1[i][2];
            float zo = acc[i][3] + (float)z1[i][3];
            float si = 1.f / (1.f + __expf(-zi));
            float sf = 1.f / (1.f + __expf(-zf));
            float so = 1.f / (1.f + __expf(-zo));
            float tg = 1.f - 2.f / (__expf(2.f * zg) + 1.f);
            c[i] = sf * c[i] + si * tg;
            float th = 1.f - 2.f / (__expf(2.f * c[i]) + 1.f);
            float h = so * th;
            hb[rb ^ 1][wrv[i]] = (half_t)h;
            if (valid) hob[gbase + cellv[i]] = (half_t)h;   // fire-and-forget
            z1[i] = z2[i]; z2[i] = zn[i];
        }
        lds_barrier();   // lgkmcnt only: global loads/stores stay in flight
    }
}

// ---------------------------------------------------------------- output projection via MFMA
__global__ __launch_bounds__(256) void k_logits(const half_t* __restrict__ h1,
                                                const half_t* __restrict__ WO,
                                                const float* __restrict__ b_out,
                                                float* __restrict__ logits) {
    int wave = threadIdx.x >> 6;
    int lane = threadIdx.x & 63;
    int m0 = blockIdx.x * 64 + wave * 16;
    int lr = lane & 15;
    int lq = lane >> 4;

    float4_t acc[2];
    acc[0] = (float4_t){0.f, 0.f, 0.f, 0.f};
    acc[1] = (float4_t){0.f, 0.f, 0.f, 0.f};

    const half_t* Arow = h1 + (size_t)(m0 + lr) * 256 + lq * 8;
    const half_t* Brow = WO + (size_t)lr * 256 + lq * 8;

    #pragma unroll
    for (int k = 0; k < 256; k += 32) {
        half8_t af = *(const half8_t*)(Arow + k);
        half8_t b0 = *(const half8_t*)(Brow + k);
        half8_t b1 = *(const half8_t*)(Brow + 16 * 256 + k);
        acc[0] = __builtin_amdgcn_mfma_f32_16x16x32_f16(af, b0, acc[0], 0, 0, 0);
        acc[1] = __builtin_amdgcn_mfma_f32_16x16x32_f16(af, b1, acc[1], 0, 0, 0);
    }
    #pragma unroll
    for (int nt = 0; nt < 2; nt++) {
        int n = nt * 16 + lr;
        float bias = b_out[n];
        #pragma unroll
        for (int i = 0; i < 4; i++) {
            int m = m0 + lq * 4 + i;
            logits[(size_t)m * KK + n] = acc[nt][i] + bias;
        }
    }
}

// ---------------------------------------------------------------- CRF forward + gold (one wave per sequence)
__global__ __launch_bounds__(64) void k_crf(const float* __restrict__ logits,
                                            const float* __restrict__ trans,
                                            const int* __restrict__ y,
                                            const int* __restrict__ lens,
                                            float* __restrict__ out) {
    int b = blockIdx.x;
    int lane = threadIdx.x;
    int k = lane & 31;
    __shared__ float TR[32][33];
    __shared__ __align__(16) float PS[32];

    for (int i = lane; i < 1024; i += 64) TR[i >> 5][i & 31] = trans[i];

    float et[32];
    const float* trow = trans + k * 32;
    #pragma unroll
    for (int j = 0; j < 32; j++) et[j] = __expf(trow[j]);   // exp(-10000) -> 0
    __syncthreads();

    int Lb = lens[b];
    const int* yb = y + b * (TT + 1);
    const float* lgb = logits + (size_t)(b * TT) * KK;

    float g = 0.f;
    for (int t = lane; t < Lb; t += 64) {
        int yt = yb[t], yt1 = yb[t + 1];
        g += lgb[(size_t)t * KK + yt1] + TR[yt1][yt];
    }
    #pragma unroll
    for (int s = 1; s < 64; s <<= 1) g += __shfl_xor(g, s);
    float gold = g + TR[3][yb[Lb]];

    float score = lgb[k] + TR[k][2];   // t=0 analytic (SOS=2)

    for (int t = 1; t < Lb; t++) {
        float lg = lgb[(size_t)t * KK + k];
        float m = __builtin_bit_cast(float, __builtin_amdgcn_readlane(__builtin_bit_cast(int, score), 4));
        float P = __expf(score - m);
        if (lane < 32) PS[k] = P;
        float4 ps[8];
        #pragma unroll
        for (int j = 0; j < 8; j++) ps[j] = *(const float4*)&PS[j * 4];
        const float* psf = (const float*)ps;
        float a0 = 0.f, a1 = 0.f, a2 = 0.f, a3 = 0.f;
        #pragma unroll
        for (int j = 0; j < 8; j++) {
            a0 = fmaf(et[j], psf[j], a0);
            a1 = fmaf(et[j + 8], psf[j + 8], a1);
            a2 = fmaf(et[j + 16], psf[j + 16], a2);
            a3 = fmaf(et[j + 24], psf[j + 24], a3);
        }
        score = lg + m + __logf((a0 + a1) + (a2 + a3));
    }

    float v = score + TR[3][k];
    float m2 = v;
    #pragma unroll
    for (int s = 1; s < 32; s <<= 1) m2 = fmaxf(m2, __shfl_xor(m2, s));
    float e = __expf(v - m2);
    #pragma unroll
    for (int s = 1; s < 32; s <<= 1) e += __shfl_xor(e, s);
    float logZ = m2 + __logf(e);

    if (lane == 0) out[b] = logZ - gold;
}

// ----------------------------------------------------------------
extern "C" void kernel_launch(void* const* d_in, const int* in_sizes, int n_in,
                              void* d_out, int out_size, void* d_ws, size_t ws_size,
                              hipStream_t stream) {
    const int*   x      = (const int*)d_in[0];
    const int*   y      = (const int*)d_in[1];
    const float* embed  = (const float*)d_in[2];
    const float* wi_l0f = (const float*)d_in[3];
    const float* wh_l0f = (const float*)d_in[4];
    const float* b_l0f  = (const float*)d_in[5];
    const float* wi_l0b = (const float*)d_in[6];
    const float* wh_l0b = (const float*)d_in[7];
    const float* b_l0b  = (const float*)d_in[8];
    const float* wi_l1f = (const float*)d_in[9];
    const float* wh_l1f = (const float*)d_in[10];
    const float* b_l1f  = (const float*)d_in[11];
    const float* wi_l1b = (const float*)d_in[12];
    const float* wh_l1b = (const float*)d_in[13];
    const float* b_l1b  = (const float*)d_in[14];
    const float* w_out  = (const float*)d_in[15];
    const float* b_out  = (const float*)d_in[16];
    const float* trans  = (const float*)d_in[17];
    float* out = (float*)d_out;

    char* base = (char*)d_ws;
    size_t off = 0;
    auto take = [&](size_t bytes) -> char* {
        char* r = base + off;
        off = (off + bytes + 255) & ~(size_t)255;
        return r;
    };
    half_t* zA  = (half_t*)take((size_t)MTOT * NWID * 2);  // 64 MiB
    half_t* h0  = (half_t*)take((size_t)MTOT * 256 * 2);   // 16 MiB
    half_t* h1  = (half_t*)take((size_t)MTOT * 256 * 2);   // 16 MiB
    half_t* e16 = (half_t*)take((size_t)MTOT * EE * 2);    // 8 MiB
    float*  lg  = (float*)take((size_t)MTOT * KK * 4);     // 4 MiB
    half_t* W0  = (half_t*)take((size_t)NWID * EE * 2);
    half_t* W1  = (half_t*)take((size_t)NWID * 256 * 2);
    half_t* WO  = (half_t*)take((size_t)KK * 256 * 2);
    int*    lens = (int*)take(BB * 4);

    k_lengths<<<BB, 256, 0, stream>>>(x, lens);
    k_pack<<<256, 256, 0, stream>>>(wi_l0f, wi_l0b, wi_l1f, wi_l1b, w_out, W0, W1, WO);
    k_embed<<<MTOT / 16, 256, 0, stream>>>(x, embed, e16);
    k_gemm<<<dim3(MTOT / 64, 4), 256, 0, stream>>>(e16, W0, b_l0f, b_l0b, zA, 128);
    k_lstm<<<8, 512, 0, stream>>>(zA, wh_l0f, wh_l0b, lens, h0);
    k_gemm<<<dim3(MTOT / 64, 4), 256, 0, stream>>>(h0, W1, b_l1f, b_l1b, zA, 256);
    k_lstm<<<8, 512, 0, stream>>>(zA, wh_l1f, wh_l1b, lens, h1);
    k_logits<<<MTOT / 64, 256, 0, stream>>>(h1, WO, b_out, lg);
    k_crf<<<BB, 64, 0, stream>>>(lg, trans, y, lens, out);
}

// Round 5
// 1485.876 us; speedup vs baseline: 1.5619x; 1.5619x over previous
//
#include <hip/hip_runtime.h>

typedef _Float16 half_t;
typedef _Float16 half2_t __attribute__((ext_vector_type(2)));
typedef _Float16 half4_t __attribute__((ext_vector_type(4)));
typedef _Float16 half8_t __attribute__((ext_vector_type(8)));
typedef float float4_t __attribute__((ext_vector_type(4)));

// Problem constants
#define BB 64
#define TT 512
#define EE 128
#define HPP 128
#define KK 32
#define MTOT (BB*TT)     // 32768
#define NWID 1024        // stacked fwd(512)+bwd(512) gate rows, gate-interleaved per dir

// barrier that drains ONLY LDS ops (z prefetch + h global stores stay in flight)
__device__ __forceinline__ void lds_barrier() {
    asm volatile("s_waitcnt lgkmcnt(0)\n\ts_barrier" ::: "memory");
}

__device__ __forceinline__ float fast_sigmoid(float x) {
    return __builtin_amdgcn_rcpf(1.f + __expf(-x));     // v_exp + v_rcp, no div sequence
}
__device__ __forceinline__ float fast_tanh(float x) {
    return 1.f - 2.f * __builtin_amdgcn_rcpf(__expf(2.f * x) + 1.f);
}

// ---------------------------------------------------------------- lengths
__global__ void k_lengths(const int* __restrict__ x, int* __restrict__ lens) {
    __shared__ int cnt;
    if (threadIdx.x == 0) cnt = 0;
    __syncthreads();
    int local = 0;
    for (int t = threadIdx.x; t < TT; t += blockDim.x)
        local += (x[blockIdx.x * TT + t] > 0) ? 1 : 0;
    atomicAdd(&cnt, local);
    __syncthreads();
    if (threadIdx.x == 0) lens[blockIdx.x] = cnt;
}

// ---------------------------------------------------------------- pack weights fp32->fp16 (wi stacked [fwd;bwd], [N,K]; w_out [32,256])
__global__ void k_pack(const float* __restrict__ wi0f, const float* __restrict__ wi0b,
                       const float* __restrict__ wi1f, const float* __restrict__ wi1b,
                       const float* __restrict__ w_out,
                       half_t* __restrict__ W0, half_t* __restrict__ W1,
                       half_t* __restrict__ WO) {
    int idx = blockIdx.x * blockDim.x + threadIdx.x;
    int stride = gridDim.x * blockDim.x;
    const int n0 = NWID * EE;
    const int n1 = NWID * 256;
    for (int i = idx; i < n0; i += stride) {
        int r = i >> 7, c = i & 127;
        float v = (r < 512) ? wi0f[r * 128 + c] : wi0b[(r - 512) * 128 + c];
        W0[i] = (half_t)v;
    }
    for (int i = idx; i < n1; i += stride) {
        int r = i >> 8, c = i & 255;
        float v = (r < 512) ? wi1f[r * 256 + c] : wi1b[(r - 512) * 256 + c];
        W1[i] = (half_t)v;
    }
    for (int i = idx; i < KK * 256; i += stride)
        WO[i] = (half_t)w_out[i];
}

// ---------------------------------------------------------------- embedding gather -> fp16
__global__ void k_embed(const int* __restrict__ x, const float* __restrict__ embed,
                        half_t* __restrict__ e16) {
    int bt = blockIdx.x * 16 + (threadIdx.x >> 4);
    int c  = (threadIdx.x & 15) * 8;
    int xi = x[bt];
    const float4* src = (const float4*)(embed + (size_t)xi * EE + c);
    float4 a = src[0], b = src[1];
    half8_t o;
    o[0] = (half_t)a.x; o[1] = (half_t)a.y; o[2] = (half_t)a.z; o[3] = (half_t)a.w;
    o[4] = (half_t)b.x; o[5] = (half_t)b.y; o[6] = (half_t)b.z; o[7] = (half_t)b.w;
    *(half8_t*)(e16 + (size_t)bt * EE + c) = o;
}

// ---------------------------------------------------------------- MFMA GEMM: C[M,1024] = A[M,Kd]*W[1024,Kd]^T + bias
// epilogue permutes n -> gate-interleaved: within each dir-half, np = cell*4 + gate
__global__ __launch_bounds__(256) void k_gemm(const half_t* __restrict__ A,
                                              const half_t* __restrict__ W,
                                              const float* __restrict__ bias_f,
                                              const float* __restrict__ bias_b,
                                              half_t* __restrict__ C, int Kd) {
    int wave = threadIdx.x >> 6;
    int lane = threadIdx.x & 63;
    int m0 = blockIdx.x * 64 + wave * 16;
    int n0 = blockIdx.y * 256;
    int lr = lane & 15;
    int lq = lane >> 4;

    float4_t acc[16];
    #pragma unroll
    for (int i = 0; i < 16; i++) acc[i] = (float4_t){0.f, 0.f, 0.f, 0.f};

    const half_t* Arow = A + (size_t)(m0 + lr) * Kd + lq * 8;
    const half_t* Wrow = W + (size_t)(n0 + lr) * Kd + lq * 8;

    for (int k = 0; k < Kd; k += 32) {
        half8_t af = *(const half8_t*)(Arow + k);
        #pragma unroll
        for (int nt = 0; nt < 16; nt++) {
            half8_t bf = *(const half8_t*)(Wrow + (size_t)nt * 16 * Kd + k);
            acc[nt] = __builtin_amdgcn_mfma_f32_16x16x32_f16(af, bf, acc[nt], 0, 0, 0);
        }
    }
    #pragma unroll
    for (int nt = 0; nt < 16; nt++) {
        int n = n0 + nt * 16 + lr;
        int n2 = (n < 512) ? n : n - 512;
        float bias = (n < 512) ? bias_f[n2] : bias_b[n2];
        int np = ((n < 512) ? 0 : 512) + (n2 & 127) * 4 + (n2 >> 7);
        #pragma unroll
        for (int i = 0; i < 4; i++) {
            int m = m0 + lq * 4 + i;
            C[(size_t)m * NWID + np] = (half_t)(acc[nt][i] + bias);
        }
    }
}

// ---------------------------------------------------------------- recurrent LSTM via MFMA, 4 chains per block, 32 blocks
// 512 thr (8 waves). Per step per wave: 4 M-tiles (64 rows = 16 cells) x 4 K-chunks = 16 MFMA.
// B cols = seq (col&3), duplicated 4x -> lane (q,col) owns cell (wv*16+(col>>2)*4+q), seq (col&3):
// exactly ONE activation per lane, no cross-lane redistribution needed.
__global__ __launch_bounds__(512, 1) void k_lstm(const half_t* __restrict__ zbuf,
                                                 const float* __restrict__ wh_f,
                                                 const float* __restrict__ wh_b,
                                                 const int* __restrict__ lens,
                                                 half_t* __restrict__ hout) {
    const int grp  = blockIdx.x >> 1;     // 16 seq-groups of 4
    const int dir  = blockIdx.x & 1;
    const int tid  = threadIdx.x;
    const int wv   = tid >> 6;
    const int lane = tid & 63;
    const int q    = lane >> 4;           // k-quad / D-row-quad
    const int col  = lane & 15;           // B column
    const int s    = col & 3;             // seq within group
    const int ii   = col >> 2;            // which M-tile this lane activates
    const int b    = grp * 4 + s;
    const int Lb   = lens[b];
    const int maxL = lens[grp * 4];       // lengths sorted descending
    const float* wh = dir ? wh_b : wh_f;

    // h in LDS: [buf][ck*128 + (s*4+q)*8 + j] halfs — b128 reads & b16 writes conflict-free-ish
    __shared__ half_t hb[2][512];

    // ---- A fragments: Wh for rows [wv*64, wv*64+64), gate-interleaved (r = cell*4+gate)
    half8_t a[4][4];
    #pragma unroll
    for (int i = 0; i < 4; i++) {
        int r = wv * 64 + i * 16 + col;            // interleaved row; A[m=col][k=q*8+j]
        int orow = (r & 3) * 128 + (r >> 2);       // original wh row = gate*128 + cell
        #pragma unroll
        for (int ck = 0; ck < 4; ck++) {
            const float4* src = (const float4*)(wh + (size_t)orow * 128 + ck * 32 + q * 8);
            float4 f0 = src[0], f1 = src[1];
            half8_t h8;
            h8[0] = (half_t)f0.x; h8[1] = (half_t)f0.y; h8[2] = (half_t)f0.z; h8[3] = (half_t)f0.w;
            h8[4] = (half_t)f1.x; h8[5] = (half_t)f1.y; h8[6] = (half_t)f1.z; h8[7] = (half_t)f1.w;
            a[i][ck] = h8;
        }
    }

    // zero h(0) buffer (one element per thread)
    hb[0][tid] = (half_t)0.f;

    const int cell = wv * 16 + ii * 4 + q;
    // LDS write offset for h(cell, s): ck' = cell>>5, q' = (cell>>3)&3, j' = cell&7
    const int woff = (cell >> 5) * 128 + (s * 4 + ((cell >> 3) & 3)) * 8 + (cell & 7);
    const int roff = (s * 4 + q) * 8;     // B-frag read offset (+ ck*128)

    float c = 0.f;
    const half_t* zb = zbuf + dir * 512;
    half_t* hob = hout + dir * 128;

    // z prefetch ring, depth 2 (one half4 = 4 gates of my cell for my seq)
    half4_t z1, z2;
    {
        int t0 = dir ? (Lb - 1) : 0;
        int t1 = dir ? (Lb - 2) : 1;      // Lb >= 256
        z1 = *(const half4_t*)(zb + (size_t)(b * TT + t0) * NWID + cell * 4);
        z2 = *(const half4_t*)(zb + (size_t)(b * TT + t1) * NWID + cell * 4);
    }
    __syncthreads();

    for (int t = 0; t < maxL; t++) {
        const int rb = t & 1;

        half8_t bf0 = *(const half8_t*)&hb[rb][roff];
        half8_t bf1 = *(const half8_t*)&hb[rb][128 + roff];
        half8_t bf2 = *(const half8_t*)&hb[rb][256 + roff];
        half8_t bf3 = *(const half8_t*)&hb[rb][384 + roff];

        float4_t acc[4];
        #pragma unroll
        for (int i = 0; i < 4; i++) acc[i] = (float4_t){0.f, 0.f, 0.f, 0.f};
        #pragma unroll
        for (int i = 0; i < 4; i++) {
            acc[i] = __builtin_amdgcn_mfma_f32_16x16x32_f16(a[i][0], bf0, acc[i], 0, 0, 0);
            acc[i] = __builtin_amdgcn_mfma_f32_16x16x32_f16(a[i][1], bf1, acc[i], 0, 0, 0);
            acc[i] = __builtin_amdgcn_mfma_f32_16x16x32_f16(a[i][2], bf2, acc[i], 0, 0, 0);
            acc[i] = __builtin_amdgcn_mfma_f32_16x16x32_f16(a[i][3], bf3, acc[i], 0, 0, 0);
        }

        // prefetch z(t+2)
        half4_t zn;
        {
            int tp = t + 2;
            int tn = dir ? (Lb - 1 - tp) : tp;
            tn = tn < 0 ? 0 : (tn > TT - 1 ? TT - 1 : tn);
            zn = *(const half4_t*)(zb + (size_t)(b * TT + tn) * NWID + cell * 4);
        }

        // select my tile's D column (uniform small select -> cndmask, no scratch)
        float4_t gg = acc[0];
        if (ii == 1) gg = acc[1];
        if (ii == 2) gg = acc[2];
        if (ii == 3) gg = acc[3];

        // activation: one cell-update per lane (gate order i,f,g,o = acc reg 0..3)
        float zi = gg[0] + (float)z1[0];
        float zf = gg[1] + (float)z1[1];
        float zg = gg[2] + (float)z1[2];
        float zo = gg[3] + (float)z1[3];
        float si = fast_sigmoid(zi);
        float sf = fast_sigmoid(zf);
        float so = fast_sigmoid(zo);
        float tg = fast_tanh(zg);
        c = sf * c + si * tg;
        float th = fast_tanh(c);
        float h = so * th;

        hb[rb ^ 1][woff] = (half_t)h;

        int tcur = dir ? (Lb - 1 - t) : t;
        if (t < Lb) hob[(size_t)(b * TT + tcur) * 256 + cell] = (half_t)h;  // fire-and-forget

        z1 = z2; z2 = zn;

        lds_barrier();   // lgkmcnt only: z loads + h stores stay in flight
    }
}

// ---------------------------------------------------------------- output projection via MFMA
__global__ __launch_bounds__(256) void k_logits(const half_t* __restrict__ h1,
                                                const half_t* __restrict__ WO,
                                                const float* __restrict__ b_out,
                                                float* __restrict__ logits) {
    int wave = threadIdx.x >> 6;
    int lane = threadIdx.x & 63;
    int m0 = blockIdx.x * 64 + wave * 16;
    int lr = lane & 15;
    int lq = lane >> 4;

    float4_t acc[2];
    acc[0] = (float4_t){0.f, 0.f, 0.f, 0.f};
    acc[1] = (float4_t){0.f, 0.f, 0.f, 0.f};

    const half_t* Arow = h1 + (size_t)(m0 + lr) * 256 + lq * 8;
    const half_t* Brow = WO + (size_t)lr * 256 + lq * 8;

    #pragma unroll
    for (int k = 0; k < 256; k += 32) {
        half8_t af = *(const half8_t*)(Arow + k);
        half8_t b0 = *(const half8_t*)(Brow + k);
        half8_t b1 = *(const half8_t*)(Brow + 16 * 256 + k);
        acc[0] = __builtin_amdgcn_mfma_f32_16x16x32_f16(af, b0, acc[0], 0, 0, 0);
        acc[1] = __builtin_amdgcn_mfma_f32_16x16x32_f16(af, b1, acc[1], 0, 0, 0);
    }
    #pragma unroll
    for (int nt = 0; nt < 2; nt++) {
        int n = nt * 16 + lr;
        float bias = b_out[n];
        #pragma unroll
        for (int i = 0; i < 4; i++) {
            int m = m0 + lq * 4 + i;
            logits[(size_t)m * KK + n] = acc[nt][i] + bias;
        }
    }
}

// ---------------------------------------------------------------- CRF forward + gold (one wave per sequence)
__global__ __launch_bounds__(64) void k_crf(const float* __restrict__ logits,
                                            const float* __restrict__ trans,
                                            const int* __restrict__ y,
                                            const int* __restrict__ lens,
                                            float* __restrict__ out) {
    int b = blockIdx.x;
    int lane = threadIdx.x;
    int k = lane & 31;
    __shared__ float TR[32][33];
    __shared__ __align__(16) float PS[32];

    for (int i = lane; i < 1024; i += 64) TR[i >> 5][i & 31] = trans[i];

    float et[32];
    const float* trow = trans + k * 32;
    #pragma unroll
    for (int j = 0; j < 32; j++) et[j] = __expf(trow[j]);   // exp(-10000) -> 0
    __syncthreads();

    int Lb = lens[b];
    const int* yb = y + b * (TT + 1);
    const float* lgb = logits + (size_t)(b * TT) * KK;

    float g = 0.f;
    for (int t = lane; t < Lb; t += 64) {
        int yt = yb[t], yt1 = yb[t + 1];
        g += lgb[(size_t)t * KK + yt1] + TR[yt1][yt];
    }
    #pragma unroll
    for (int s = 1; s < 64; s <<= 1) g += __shfl_xor(g, s);
    float gold = g + TR[3][yb[Lb]];

    float score = lgb[k] + TR[k][2];   // t=0 analytic (SOS=2)

    for (int t = 1; t < Lb; t++) {
        float lg = lgb[(size_t)t * KK + k];
        float m = __builtin_bit_cast(float, __builtin_amdgcn_readlane(__builtin_bit_cast(int, score), 4));
        float P = __expf(score - m);
        if (lane < 32) PS[k] = P;
        float4 ps[8];
        #pragma unroll
        for (int j = 0; j < 8; j++) ps[j] = *(const float4*)&PS[j * 4];
        const float* psf = (const float*)ps;
        float a0 = 0.f, a1 = 0.f, a2 = 0.f, a3 = 0.f;
        #pragma unroll
        for (int j = 0; j < 8; j++) {
            a0 = fmaf(et[j], psf[j], a0);
            a1 = fmaf(et[j + 8], psf[j + 8], a1);
            a2 = fmaf(et[j + 16], psf[j + 16], a2);
            a3 = fmaf(et[j + 24], psf[j + 24], a3);
        }
        score = lg + m + __logf((a0 + a1) + (a2 + a3));
    }

    float v = score + TR[3][k];
    float m2 = v;
    #pragma unroll
    for (int s = 1; s < 32; s <<= 1) m2 = fmaxf(m2, __shfl_xor(m2, s));
    float e = __expf(v - m2);
    #pragma unroll
    for (int s = 1; s < 32; s <<= 1) e += __shfl_xor(e, s);
    float logZ = m2 + __logf(e);

    if (lane == 0) out[b] = logZ - gold;
}

// ----------------------------------------------------------------
extern "C" void kernel_launch(void* const* d_in, const int* in_sizes, int n_in,
                              void* d_out, int out_size, void* d_ws, size_t ws_size,
                              hipStream_t stream) {
    const int*   x      = (const int*)d_in[0];
    const int*   y      = (const int*)d_in[1];
    const float* embed  = (const float*)d_in[2];
    const float* wi_l0f = (const float*)d_in[3];
    const float* wh_l0f = (const float*)d_in[4];
    const float* b_l0f  = (const float*)d_in[5];
    const float* wi_l0b = (const float*)d_in[6];
    const float* wh_l0b = (const float*)d_in[7];
    const float* b_l0b  = (const float*)d_in[8];
    const float* wi_l1f = (const float*)d_in[9];
    const float* wh_l1f = (const float*)d_in[10];
    const float* b_l1f  = (const float*)d_in[11];
    const float* wi_l1b = (const float*)d_in[12];
    const float* wh_l1b = (const float*)d_in[13];
    const float* b_l1b  = (const float*)d_in[14];
    const float* w_out  = (const float*)d_in[15];
    const float* b_out  = (const float*)d_in[16];
    const float* trans  = (const float*)d_in[17];
    float* out = (float*)d_out;

    char* base = (char*)d_ws;
    size_t off = 0;
    auto take = [&](size_t bytes) -> char* {
        char* r = base + off;
        off = (off + bytes + 255) & ~(size_t)255;
        return r;
    };
    half_t* zA  = (half_t*)take((size_t)MTOT * NWID * 2);  // 64 MiB
    half_t* h0  = (half_t*)take((size_t)MTOT * 256 * 2);   // 16 MiB
    half_t* h1  = (half_t*)take((size_t)MTOT * 256 * 2);   // 16 MiB
    half_t* e16 = (half_t*)take((size_t)MTOT * EE * 2);    // 8 MiB
    float*  lg  = (float*)take((size_t)MTOT * KK * 4);     // 4 MiB
    half_t* W0  = (half_t*)take((size_t)NWID * EE * 2);
    half_t* W1  = (half_t*)take((size_t)NWID * 256 * 2);
    half_t* WO  = (half_t*)take((size_t)KK * 256 * 2);
    int*    lens = (int*)take(BB * 4);

    k_lengths<<<BB, 256, 0, stream>>>(x, lens);
    k_pack<<<256, 256, 0, stream>>>(wi_l0f, wi_l0b, wi_l1f, wi_l1b, w_out, W0, W1, WO);
    k_embed<<<MTOT / 16, 256, 0, stream>>>(x, embed, e16);
    k_gemm<<<dim3(MTOT / 64, 4), 256, 0, stream>>>(e16, W0, b_l0f, b_l0b, zA, 128);
    k_lstm<<<32, 512, 0, stream>>>(zA, wh_l0f, wh_l0b, lens, h0);
    k_gemm<<<dim3(MTOT / 64, 4), 256, 0, stream>>>(h0, W1, b_l1f, b_l1b, zA, 256);
    k_lstm<<<32, 512, 0, stream>>>(zA, wh_l1f, wh_l1b, lens, h1);
    k_logits<<<MTOT / 64, 256, 0, stream>>>(h1, WO, b_out, lg);
    k_crf<<<BB, 64, 0, stream>>>(lg, trans, y, lens, out);
}

// Round 6
// 1189.988 us; speedup vs baseline: 1.9502x; 1.2486x over previous
//
#include <hip/hip_runtime.h>

typedef _Float16 half_t;
typedef _Float16 half2_t __attribute__((ext_vector_type(2)));
typedef _Float16 half4_t __attribute__((ext_vector_type(4)));
typedef _Float16 half8_t __attribute__((ext_vector_type(8)));
typedef float float4_t __attribute__((ext_vector_type(4)));

// Problem constants
#define BB 64
#define TT 512
#define EE 128
#define HPP 128
#define KK 32
#define MTOT (BB*TT)     // 32768
#define NWID 1024        // stacked fwd(512)+bwd(512) gate rows, gate-interleaved per dir

// barrier that drains ONLY LDS ops (z prefetch + h global stores stay in flight)
__device__ __forceinline__ void lds_barrier() {
    asm volatile("s_waitcnt lgkmcnt(0)\n\ts_barrier" ::: "memory");
}

__device__ __forceinline__ float fast_sigmoid(float x) {
    return __builtin_amdgcn_rcpf(1.f + __expf(-x));     // v_exp + v_rcp, no div sequence
}
__device__ __forceinline__ float fast_tanh(float x) {
    return 1.f - 2.f * __builtin_amdgcn_rcpf(__expf(2.f * x) + 1.f);
}

// ---------------------------------------------------------------- lengths
__global__ void k_lengths(const int* __restrict__ x, int* __restrict__ lens) {
    __shared__ int cnt;
    if (threadIdx.x == 0) cnt = 0;
    __syncthreads();
    int local = 0;
    for (int t = threadIdx.x; t < TT; t += blockDim.x)
        local += (x[blockIdx.x * TT + t] > 0) ? 1 : 0;
    atomicAdd(&cnt, local);
    __syncthreads();
    if (threadIdx.x == 0) lens[blockIdx.x] = cnt;
}

// ---------------------------------------------------------------- pack weights fp32->fp16 (wi stacked [fwd;bwd], [N,K]; w_out [32,256])
__global__ void k_pack(const float* __restrict__ wi0f, const float* __restrict__ wi0b,
                       const float* __restrict__ wi1f, const float* __restrict__ wi1b,
                       const float* __restrict__ w_out,
                       half_t* __restrict__ W0, half_t* __restrict__ W1,
                       half_t* __restrict__ WO) {
    int idx = blockIdx.x * blockDim.x + threadIdx.x;
    int stride = gridDim.x * blockDim.x;
    const int n0 = NWID * EE;
    const int n1 = NWID * 256;
    for (int i = idx; i < n0; i += stride) {
        int r = i >> 7, c = i & 127;
        float v = (r < 512) ? wi0f[r * 128 + c] : wi0b[(r - 512) * 128 + c];
        W0[i] = (half_t)v;
    }
    for (int i = idx; i < n1; i += stride) {
        int r = i >> 8, c = i & 255;
        float v = (r < 512) ? wi1f[r * 256 + c] : wi1b[(r - 512) * 256 + c];
        W1[i] = (half_t)v;
    }
    for (int i = idx; i < KK * 256; i += stride)
        WO[i] = (half_t)w_out[i];
}

// ---------------------------------------------------------------- embedding gather -> fp16
__global__ void k_embed(const int* __restrict__ x, const float* __restrict__ embed,
                        half_t* __restrict__ e16) {
    int bt = blockIdx.x * 16 + (threadIdx.x >> 4);
    int c  = (threadIdx.x & 15) * 8;
    int xi = x[bt];
    const float4* src = (const float4*)(embed + (size_t)xi * EE + c);
    float4 a = src[0], b = src[1];
    half8_t o;
    o[0] = (half_t)a.x; o[1] = (half_t)a.y; o[2] = (half_t)a.z; o[3] = (half_t)a.w;
    o[4] = (half_t)b.x; o[5] = (half_t)b.y; o[6] = (half_t)b.z; o[7] = (half_t)b.w;
    *(half8_t*)(e16 + (size_t)bt * EE + c) = o;
}

// ---------------------------------------------------------------- MFMA GEMM: C[M,1024] = A[M,Kd]*W[1024,Kd]^T + bias
// epilogue permutes n -> gate-interleaved: within each dir-half, np = cell*4 + gate
__global__ __launch_bounds__(256) void k_gemm(const half_t* __restrict__ A,
                                              const half_t* __restrict__ W,
                                              const float* __restrict__ bias_f,
                                              const float* __restrict__ bias_b,
                                              half_t* __restrict__ C, int Kd) {
    int wave = threadIdx.x >> 6;
    int lane = threadIdx.x & 63;
    int m0 = blockIdx.x * 64 + wave * 16;
    int n0 = blockIdx.y * 256;
    int lr = lane & 15;
    int lq = lane >> 4;

    float4_t acc[16];
    #pragma unroll
    for (int i = 0; i < 16; i++) acc[i] = (float4_t){0.f, 0.f, 0.f, 0.f};

    const half_t* Arow = A + (size_t)(m0 + lr) * Kd + lq * 8;
    const half_t* Wrow = W + (size_t)(n0 + lr) * Kd + lq * 8;

    for (int k = 0; k < Kd; k += 32) {
        half8_t af = *(const half8_t*)(Arow + k);
        #pragma unroll
        for (int nt = 0; nt < 16; nt++) {
            half8_t bf = *(const half8_t*)(Wrow + (size_t)nt * 16 * Kd + k);
            acc[nt] = __builtin_amdgcn_mfma_f32_16x16x32_f16(af, bf, acc[nt], 0, 0, 0);
        }
    }
    #pragma unroll
    for (int nt = 0; nt < 16; nt++) {
        int n = n0 + nt * 16 + lr;
        int n2 = (n < 512) ? n : n - 512;
        float bias = (n < 512) ? bias_f[n2] : bias_b[n2];
        int np = ((n < 512) ? 0 : 512) + (n2 & 127) * 4 + (n2 >> 7);
        #pragma unroll
        for (int i = 0; i < 4; i++) {
            int m = m0 + lq * 4 + i;
            C[(size_t)m * NWID + np] = (half_t)(acc[nt][i] + bias);
        }
    }
}

// ---------------------------------------------------------------- recurrent LSTM via MFMA, 4 chains per block, 32 blocks
// 512 thr (8 waves). Per step per wave: 4 M-tiles (64 rows = 16 cells) x 4 K-chunks = 16 MFMA.
// B cols carry seq (col&3) duplicated 4x; lane (q,col) owns cell (wv*16+(col>>2)*4+q), seq (col&3).
// R6: accs as NAMED variables (A0..A3) + scalar ternary selects — prevents the compiler
//     demoting the acc array to per-lane LDS scratch (R5: +32KB LDS, 9.6M bank conflicts).
__global__ __launch_bounds__(512, 1) void k_lstm(const half_t* __restrict__ zbuf,
                                                 const float* __restrict__ wh_f,
                                                 const float* __restrict__ wh_b,
                                                 const int* __restrict__ lens,
                                                 half_t* __restrict__ hout) {
    const int grp  = blockIdx.x >> 1;     // 16 seq-groups of 4
    const int dir  = blockIdx.x & 1;
    const int tid  = threadIdx.x;
    const int wv   = tid >> 6;
    const int lane = tid & 63;
    const int q    = lane >> 4;           // k-quad / D-row-quad
    const int col  = lane & 15;           // B column
    const int s    = col & 3;             // seq within group
    const int ii   = col >> 2;            // which M-tile this lane activates
    const int b    = grp * 4 + s;
    const int Lb   = lens[b];
    const int maxL = lens[grp * 4];       // lengths sorted descending
    const float* wh = dir ? wh_b : wh_f;

    __shared__ half_t hb[2][512];   // [buf][ck*128 + (s*4+q)*8 + j]

    // ---- A fragments: Wh rows [wv*64, wv*64+64), gate-interleaved (r = cell*4+gate)
    half8_t a0[4], a1[4], a2[4], a3[4];
    #pragma unroll
    for (int i = 0; i < 4; i++) {
        int r = wv * 64 + i * 16 + col;            // interleaved row; A[m=col][k=q*8+j]
        int orow = (r & 3) * 128 + (r >> 2);       // original wh row = gate*128 + cell
        #pragma unroll
        for (int ck = 0; ck < 4; ck++) {
            const float4* src = (const float4*)(wh + (size_t)orow * 128 + ck * 32 + q * 8);
            float4 f0 = src[0], f1 = src[1];
            half8_t h8;
            h8[0] = (half_t)f0.x; h8[1] = (half_t)f0.y; h8[2] = (half_t)f0.z; h8[3] = (half_t)f0.w;
            h8[4] = (half_t)f1.x; h8[5] = (half_t)f1.y; h8[6] = (half_t)f1.z; h8[7] = (half_t)f1.w;
            if (i == 0) a0[ck] = h8;
            else if (i == 1) a1[ck] = h8;
            else if (i == 2) a2[ck] = h8;
            else a3[ck] = h8;
        }
    }

    hb[0][tid] = (half_t)0.f;   // zero h(0) buffer

    const int cell = wv * 16 + ii * 4 + q;
    const int woff = (cell >> 5) * 128 + (s * 4 + ((cell >> 3) & 3)) * 8 + (cell & 7);
    const int roff = (s * 4 + q) * 8;     // B-frag read offset (+ ck*128)

    float c = 0.f;
    const half_t* zb = zbuf + dir * 512;
    half_t* hob = hout + dir * 128;

    // z prefetch ring, depth 2 (one half4 = 4 gates of my cell for my seq)
    half4_t z1, z2;
    {
        int t0 = dir ? (Lb - 1) : 0;
        int t1 = dir ? (Lb - 2) : 1;      // Lb >= 256
        z1 = *(const half4_t*)(zb + (size_t)(b * TT + t0) * NWID + cell * 4);
        z2 = *(const half4_t*)(zb + (size_t)(b * TT + t1) * NWID + cell * 4);
    }
    __syncthreads();

    for (int t = 0; t < maxL; t++) {
        const int rb = t & 1;

        half8_t bf0 = *(const half8_t*)&hb[rb][roff];
        half8_t bf1 = *(const half8_t*)&hb[rb][128 + roff];
        half8_t bf2 = *(const half8_t*)&hb[rb][256 + roff];
        half8_t bf3 = *(const half8_t*)&hb[rb][384 + roff];

        float4_t A0 = (float4_t){0.f, 0.f, 0.f, 0.f};
        float4_t A1 = (float4_t){0.f, 0.f, 0.f, 0.f};
        float4_t A2 = (float4_t){0.f, 0.f, 0.f, 0.f};
        float4_t A3 = (float4_t){0.f, 0.f, 0.f, 0.f};

        A0 = __builtin_amdgcn_mfma_f32_16x16x32_f16(a0[0], bf0, A0, 0, 0, 0);
        A1 = __builtin_amdgcn_mfma_f32_16x16x32_f16(a1[0], bf0, A1, 0, 0, 0);
        A2 = __builtin_amdgcn_mfma_f32_16x16x32_f16(a2[0], bf0, A2, 0, 0, 0);
        A3 = __builtin_amdgcn_mfma_f32_16x16x32_f16(a3[0], bf0, A3, 0, 0, 0);
        A0 = __builtin_amdgcn_mfma_f32_16x16x32_f16(a0[1], bf1, A0, 0, 0, 0);
        A1 = __builtin_amdgcn_mfma_f32_16x16x32_f16(a1[1], bf1, A1, 0, 0, 0);
        A2 = __builtin_amdgcn_mfma_f32_16x16x32_f16(a2[1], bf1, A2, 0, 0, 0);
        A3 = __builtin_amdgcn_mfma_f32_16x16x32_f16(a3[1], bf1, A3, 0, 0, 0);
        A0 = __builtin_amdgcn_mfma_f32_16x16x32_f16(a0[2], bf2, A0, 0, 0, 0);
        A1 = __builtin_amdgcn_mfma_f32_16x16x32_f16(a1[2], bf2, A1, 0, 0, 0);
        A2 = __builtin_amdgcn_mfma_f32_16x16x32_f16(a2[2], bf2, A2, 0, 0, 0);
        A3 = __builtin_amdgcn_mfma_f32_16x16x32_f16(a3[2], bf2, A3, 0, 0, 0);
        A0 = __builtin_amdgcn_mfma_f32_16x16x32_f16(a0[3], bf3, A0, 0, 0, 0);
        A1 = __builtin_amdgcn_mfma_f32_16x16x32_f16(a1[3], bf3, A1, 0, 0, 0);
        A2 = __builtin_amdgcn_mfma_f32_16x16x32_f16(a2[3], bf3, A2, 0, 0, 0);
        A3 = __builtin_amdgcn_mfma_f32_16x16x32_f16(a3[3], bf3, A3, 0, 0, 0);

        // prefetch z(t+2)
        half4_t zn;
        {
            int tp = t + 2;
            int tn = dir ? (Lb - 1 - tp) : tp;
            tn = tn < 0 ? 0 : (tn > TT - 1 ? TT - 1 : tn);
            zn = *(const half4_t*)(zb + (size_t)(b * TT + tn) * NWID + cell * 4);
        }

        // per-scalar ternary selects (12 v_cndmask) — no addressable array, no demotion
        bool s1 = (ii == 1), s2 = (ii == 2), s3 = (ii == 3);
        float g0 = s1 ? A1[0] : (s2 ? A2[0] : (s3 ? A3[0] : A0[0]));
        float g1 = s1 ? A1[1] : (s2 ? A2[1] : (s3 ? A3[1] : A0[1]));
        float g2 = s1 ? A1[2] : (s2 ? A2[2] : (s3 ? A3[2] : A0[2]));
        float g3 = s1 ? A1[3] : (s2 ? A2[3] : (s3 ? A3[3] : A0[3]));

        // activation: one cell-update per lane (gate order i,f,g,o)
        float zi = g0 + (float)z1[0];
        float zf = g1 + (float)z1[1];
        float zg = g2 + (float)z1[2];
        float zo = g3 + (float)z1[3];
        float si = fast_sigmoid(zi);
        float sf = fast_sigmoid(zf);
        float so = fast_sigmoid(zo);
        float tg = fast_tanh(zg);
        c = sf * c + si * tg;
        float th = fast_tanh(c);
        float h = so * th;

        hb[rb ^ 1][woff] = (half_t)h;

        int tcur = dir ? (Lb - 1 - t) : t;
        if (t < Lb) hob[(size_t)(b * TT + tcur) * 256 + cell] = (half_t)h;  // fire-and-forget

        z1 = z2; z2 = zn;

        lds_barrier();   // lgkmcnt only: z loads + h stores stay in flight
    }
}

// ---------------------------------------------------------------- output projection via MFMA
__global__ __launch_bounds__(256) void k_logits(const half_t* __restrict__ h1,
                                                const half_t* __restrict__ WO,
                                                const float* __restrict__ b_out,
                                                float* __restrict__ logits) {
    int wave = threadIdx.x >> 6;
    int lane = threadIdx.x & 63;
    int m0 = blockIdx.x * 64 + wave * 16;
    int lr = lane & 15;
    int lq = lane >> 4;

    float4_t acc0 = (float4_t){0.f, 0.f, 0.f, 0.f};
    float4_t acc1 = (float4_t){0.f, 0.f, 0.f, 0.f};

    const half_t* Arow = h1 + (size_t)(m0 + lr) * 256 + lq * 8;
    const half_t* Brow = WO + (size_t)lr * 256 + lq * 8;

    #pragma unroll
    for (int k = 0; k < 256; k += 32) {
        half8_t af = *(const half8_t*)(Arow + k);
        half8_t b0 = *(const half8_t*)(Brow + k);
        half8_t b1 = *(const half8_t*)(Brow + 16 * 256 + k);
        acc0 = __builtin_amdgcn_mfma_f32_16x16x32_f16(af, b0, acc0, 0, 0, 0);
        acc1 = __builtin_amdgcn_mfma_f32_16x16x32_f16(af, b1, acc1, 0, 0, 0);
    }
    #pragma unroll
    for (int nt = 0; nt < 2; nt++) {
        int n = nt * 16 + lr;
        float bias = b_out[n];
        #pragma unroll
        for (int i = 0; i < 4; i++) {
            int m = m0 + lq * 4 + i;
            logits[(size_t)m * KK + n] = (nt == 0 ? acc0[i] : acc1[i]) + bias;
        }
    }
}

// ---------------------------------------------------------------- CRF forward + gold (one wave per sequence)
__global__ __launch_bounds__(64) void k_crf(const float* __restrict__ logits,
                                            const float* __restrict__ trans,
                                            const int* __restrict__ y,
                                            const int* __restrict__ lens,
                                            float* __restrict__ out) {
    int b = blockIdx.x;
    int lane = threadIdx.x;
    int k = lane & 31;
    __shared__ float TR[32][33];
    __shared__ __align__(16) float PS[32];

    for (int i = lane; i < 1024; i += 64) TR[i >> 5][i & 31] = trans[i];

    float et[32];
    const float* trow = trans + k * 32;
    #pragma unroll
    for (int j = 0; j < 32; j++) et[j] = __expf(trow[j]);   // exp(-10000) -> 0
    __syncthreads();

    int Lb = lens[b];
    const int* yb = y + b * (TT + 1);
    const float* lgb = logits + (size_t)(b * TT) * KK;

    float g = 0.f;
    for (int t = lane; t < Lb; t += 64) {
        int yt = yb[t], yt1 = yb[t + 1];
        g += lgb[(size_t)t * KK + yt1] + TR[yt1][yt];
    }
    #pragma unroll
    for (int s = 1; s < 64; s <<= 1) g += __shfl_xor(g, s);
    float gold = g + TR[3][yb[Lb]];

    float score = lgb[k] + TR[k][2];   // t=0 analytic (SOS=2)

    for (int t = 1; t < Lb; t++) {
        float lg = lgb[(size_t)t * KK + k];
        float m = __builtin_bit_cast(float, __builtin_amdgcn_readlane(__builtin_bit_cast(int, score), 4));
        float P = __expf(score - m);
        if (lane < 32) PS[k] = P;
        float4 ps[8];
        #pragma unroll
        for (int j = 0; j < 8; j++) ps[j] = *(const float4*)&PS[j * 4];
        const float* psf = (const float*)ps;
        float a0 = 0.f, a1 = 0.f, a2 = 0.f, a3 = 0.f;
        #pragma unroll
        for (int j = 0; j < 8; j++) {
            a0 = fmaf(et[j], psf[j], a0);
            a1 = fmaf(et[j + 8], psf[j + 8], a1);
            a2 = fmaf(et[j + 16], psf[j + 16], a2);
            a3 = fmaf(et[j + 24], psf[j + 24], a3);
        }
        score = lg + m + __logf((a0 + a1) + (a2 + a3));
    }

    float v = score + TR[3][k];
    float m2 = v;
    #pragma unroll
    for (int s = 1; s < 32; s <<= 1) m2 = fmaxf(m2, __shfl_xor(m2, s));
    float e = __expf(v - m2);
    #pragma unroll
    for (int s = 1; s < 32; s <<= 1) e += __shfl_xor(e, s);
    float logZ = m2 + __logf(e);

    if (lane == 0) out[b] = logZ - gold;
}

// ----------------------------------------------------------------
extern "C" void kernel_launch(void* const* d_in, const int* in_sizes, int n_in,
                              void* d_out, int out_size, void* d_ws, size_t ws_size,
                              hipStream_t stream) {
    const int*   x      = (const int*)d_in[0];
    const int*   y      = (const int*)d_in[1];
    const float* embed  = (const float*)d_in[2];
    const float* wi_l0f = (const float*)d_in[3];
    const float* wh_l0f = (const float*)d_in[4];
    const float* b_l0f  = (const float*)d_in[5];
    const float* wi_l0b = (const float*)d_in[6];
    const float* wh_l0b = (const float*)d_in[7];
    const float* b_l0b  = (const float*)d_in[8];
    const float* wi_l1f = (const float*)d_in[9];
    const float* wh_l1f = (const float*)d_in[10];
    const float* b_l1f  = (const float*)d_in[11];
    const float* wi_l1b = (const float*)d_in[12];
    const float* wh_l1b = (const float*)d_in[13];
    const float* b_l1b  = (const float*)d_in[14];
    const float* w_out  = (const float*)d_in[15];
    const float* b_out  = (const float*)d_in[16];
    const float* trans  = (const float*)d_in[17];
    float* out = (float*)d_out;

    char* base = (char*)d_ws;
    size_t off = 0;
    auto take = [&](size_t bytes) -> char* {
        char* r = base + off;
        off = (off + bytes + 255) & ~(size_t)255;
        return r;
    };
    half_t* zA  = (half_t*)take((size_t)MTOT * NWID * 2);  // 64 MiB
    half_t* h0  = (half_t*)take((size_t)MTOT * 256 * 2);   // 16 MiB
    half_t* h1  = (half_t*)take((size_t)MTOT * 256 * 2);   // 16 MiB
    half_t* e16 = (half_t*)take((size_t)MTOT * EE * 2);    // 8 MiB
    float*  lg  = (float*)take((size_t)MTOT * KK * 4);     // 4 MiB
    half_t* W0  = (half_t*)take((size_t)NWID * EE * 2);
    half_t* W1  = (half_t*)take((size_t)NWID * 256 * 2);
    half_t* WO  = (half_t*)take((size_t)KK * 256 * 2);
    int*    lens = (int*)take(BB * 4);

    k_lengths<<<BB, 256, 0, stream>>>(x, lens);
    k_pack<<<256, 256, 0, stream>>>(wi_l0f, wi_l0b, wi_l1f, wi_l1b, w_out, W0, W1, WO);
    k_embed<<<MTOT / 16, 256, 0, stream>>>(x, embed, e16);
    k_gemm<<<dim3(MTOT / 64, 4), 256, 0, stream>>>(e16, W0, b_l0f, b_l0b, zA, 128);
    k_lstm<<<32, 512, 0, stream>>>(zA, wh_l0f, wh_l0b, lens, h0);
    k_gemm<<<dim3(MTOT / 64, 4), 256, 0, stream>>>(h0, W1, b_l1f, b_l1b, zA, 256);
    k_lstm<<<32, 512, 0, stream>>>(zA, wh_l1f, wh_l1b, lens, h1);
    k_logits<<<MTOT / 64, 256, 0, stream>>>(h1, WO, b_out, lg);
    k_crf<<<BB, 64, 0, stream>>>(lg, trans, y, lens, out);
}

// Round 7
// 1002.640 us; speedup vs baseline: 2.3147x; 1.1869x over previous
//
#include <hip/hip_runtime.h>

typedef _Float16 half_t;
typedef _Float16 half2_t __attribute__((ext_vector_type(2)));
typedef _Float16 half4_t __attribute__((ext_vector_type(4)));
typedef _Float16 half8_t __attribute__((ext_vector_type(8)));
typedef float float4_t __attribute__((ext_vector_type(4)));

// Problem constants
#define BB 64
#define TT 512
#define EE 128
#define HPP 128
#define KK 32
#define MTOT (BB*TT)     // 32768
#define NWID 1024        // stacked fwd(512)+bwd(512) gate rows, gate-interleaved per dir

// barrier that drains ONLY LDS ops (z prefetch + h global stores stay in flight)
__device__ __forceinline__ void lds_barrier() {
    asm volatile("s_waitcnt lgkmcnt(0)\n\ts_barrier" ::: "memory");
}

__device__ __forceinline__ float fast_sigmoid(float x) {
    return __builtin_amdgcn_rcpf(1.f + __expf(-x));     // v_exp + v_rcp, no div sequence
}
__device__ __forceinline__ float fast_tanh(float x) {
    return 1.f - 2.f * __builtin_amdgcn_rcpf(__expf(2.f * x) + 1.f);
}

// ---------------------------------------------------------------- lengths
__global__ void k_lengths(const int* __restrict__ x, int* __restrict__ lens) {
    __shared__ int cnt;
    if (threadIdx.x == 0) cnt = 0;
    __syncthreads();
    int local = 0;
    for (int t = threadIdx.x; t < TT; t += blockDim.x)
        local += (x[blockIdx.x * TT + t] > 0) ? 1 : 0;
    atomicAdd(&cnt, local);
    __syncthreads();
    if (threadIdx.x == 0) lens[blockIdx.x] = cnt;
}

// ---------------------------------------------------------------- pack weights fp32->fp16 (wi stacked [fwd;bwd], [N,K]; w_out [32,256])
__global__ void k_pack(const float* __restrict__ wi0f, const float* __restrict__ wi0b,
                       const float* __restrict__ wi1f, const float* __restrict__ wi1b,
                       const float* __restrict__ w_out,
                       half_t* __restrict__ W0, half_t* __restrict__ W1,
                       half_t* __restrict__ WO) {
    int idx = blockIdx.x * blockDim.x + threadIdx.x;
    int stride = gridDim.x * blockDim.x;
    const int n0 = NWID * EE;
    const int n1 = NWID * 256;
    for (int i = idx; i < n0; i += stride) {
        int r = i >> 7, c = i & 127;
        float v = (r < 512) ? wi0f[r * 128 + c] : wi0b[(r - 512) * 128 + c];
        W0[i] = (half_t)v;
    }
    for (int i = idx; i < n1; i += stride) {
        int r = i >> 8, c = i & 255;
        float v = (r < 512) ? wi1f[r * 256 + c] : wi1b[(r - 512) * 256 + c];
        W1[i] = (half_t)v;
    }
    for (int i = idx; i < KK * 256; i += stride)
        WO[i] = (half_t)w_out[i];
}

// ---------------------------------------------------------------- embedding gather -> fp16
__global__ void k_embed(const int* __restrict__ x, const float* __restrict__ embed,
                        half_t* __restrict__ e16) {
    int bt = blockIdx.x * 16 + (threadIdx.x >> 4);
    int c  = (threadIdx.x & 15) * 8;
    int xi = x[bt];
    const float4* src = (const float4*)(embed + (size_t)xi * EE + c);
    float4 a = src[0], b = src[1];
    half8_t o;
    o[0] = (half_t)a.x; o[1] = (half_t)a.y; o[2] = (half_t)a.z; o[3] = (half_t)a.w;
    o[4] = (half_t)b.x; o[5] = (half_t)b.y; o[6] = (half_t)b.z; o[7] = (half_t)b.w;
    *(half8_t*)(e16 + (size_t)bt * EE + c) = o;
}

// ---------------------------------------------------------------- MFMA GEMM: C[M,1024] = A[M,Kd]*W[1024,Kd]^T + bias
// epilogue permutes n -> gate-interleaved: within each dir-half, np = cell*4 + gate
__global__ __launch_bounds__(256) void k_gemm(const half_t* __restrict__ A,
                                              const half_t* __restrict__ W,
                                              const float* __restrict__ bias_f,
                                              const float* __restrict__ bias_b,
                                              half_t* __restrict__ C, int Kd) {
    int wave = threadIdx.x >> 6;
    int lane = threadIdx.x & 63;
    int m0 = blockIdx.x * 64 + wave * 16;
    int n0 = blockIdx.y * 256;
    int lr = lane & 15;
    int lq = lane >> 4;

    float4_t acc[16];
    #pragma unroll
    for (int i = 0; i < 16; i++) acc[i] = (float4_t){0.f, 0.f, 0.f, 0.f};

    const half_t* Arow = A + (size_t)(m0 + lr) * Kd + lq * 8;
    const half_t* Wrow = W + (size_t)(n0 + lr) * Kd + lq * 8;

    for (int k = 0; k < Kd; k += 32) {
        half8_t af = *(const half8_t*)(Arow + k);
        #pragma unroll
        for (int nt = 0; nt < 16; nt++) {
            half8_t bf = *(const half8_t*)(Wrow + (size_t)nt * 16 * Kd + k);
            acc[nt] = __builtin_amdgcn_mfma_f32_16x16x32_f16(af, bf, acc[nt], 0, 0, 0);
        }
    }
    #pragma unroll
    for (int nt = 0; nt < 16; nt++) {
        int n = n0 + nt * 16 + lr;
        int n2 = (n < 512) ? n : n - 512;
        float bias = (n < 512) ? bias_f[n2] : bias_b[n2];
        int np = ((n < 512) ? 0 : 512) + (n2 & 127) * 4 + (n2 >> 7);
        #pragma unroll
        for (int i = 0; i < 4; i++) {
            int m = m0 + lq * 4 + i;
            C[(size_t)m * NWID + np] = (half_t)(acc[nt][i] + bias);
        }
    }
}

// ---------------------------------------------------------------- recurrent LSTM via MFMA, 4 chains per block, 32 blocks
// R7: strength-reduced u32 byte offsets (SGPR base + VGPR offset, +=delta per step),
//     2-step unroll (no z-ring moves), always-store with dead-row redirect.
__global__ __launch_bounds__(512, 1) void k_lstm(const half_t* __restrict__ zbuf,
                                                 const float* __restrict__ wh_f,
                                                 const float* __restrict__ wh_b,
                                                 const int* __restrict__ lens,
                                                 half_t* __restrict__ hout) {
    const int grp  = blockIdx.x >> 1;     // 16 seq-groups of 4
    const int dir  = blockIdx.x & 1;
    const int tid  = threadIdx.x;
    const int wv   = tid >> 6;
    const int lane = tid & 63;
    const int q    = lane >> 4;           // k-quad / D-row-quad
    const int col  = lane & 15;           // B column
    const int s    = col & 3;             // seq within group
    const int ii   = col >> 2;            // which M-tile this lane activates
    const int b    = grp * 4 + s;
    const int Lb   = lens[b];
    const int maxL = lens[grp * 4];       // lengths sorted descending
    const float* wh = dir ? wh_b : wh_f;

    __shared__ half_t hb[2][512];   // [buf][ck*128 + (s*4+q)*8 + j]

    // ---- A fragments: Wh rows [wv*64, wv*64+64), gate-interleaved (r = cell*4+gate)
    half8_t a0[4], a1[4], a2[4], a3[4];
    #pragma unroll
    for (int i = 0; i < 4; i++) {
        int r = wv * 64 + i * 16 + col;            // interleaved row; A[m=col][k=q*8+j]
        int orow = (r & 3) * 128 + (r >> 2);       // original wh row = gate*128 + cell
        #pragma unroll
        for (int ck = 0; ck < 4; ck++) {
            const float4* src = (const float4*)(wh + (size_t)orow * 128 + ck * 32 + q * 8);
            float4 f0 = src[0], f1 = src[1];
            half8_t h8;
            h8[0] = (half_t)f0.x; h8[1] = (half_t)f0.y; h8[2] = (half_t)f0.z; h8[3] = (half_t)f0.w;
            h8[4] = (half_t)f1.x; h8[5] = (half_t)f1.y; h8[6] = (half_t)f1.z; h8[7] = (half_t)f1.w;
            if (i == 0) a0[ck] = h8;
            else if (i == 1) a1[ck] = h8;
            else if (i == 2) a2[ck] = h8;
            else a3[ck] = h8;
        }
    }

    hb[0][tid] = (half_t)0.f;   // zero h(0) buffer

    const int cell = wv * 16 + ii * 4 + q;
    const int woff = (cell >> 5) * 128 + (s * 4 + ((cell >> 3) & 3)) * 8 + (cell & 7);
    const int roff = (s * 4 + q) * 8;     // B-frag read offset (+ ck*128)

    const bool s1 = (ii == 1), s2 = (ii == 2), s3 = (ii == 3);

    float c = 0.f;
    const char* zb8  = (const char*)zbuf + dir * 1024;   // + per-lane u32 byte offset
    char*       hob8 = (char*)hout + dir * 256;

    const int zdelta = dir ? -2048 : 2048;
    const int hdelta = dir ? -512 : 512;

    // prologue: load z(0), z(1) directly
    int t0 = dir ? (Lb - 1) : 0;
    int t1 = dir ? (Lb - 2) : 1;          // Lb >= 256, safe
    half4_t z1 = *(const half4_t*)(zb8 + (unsigned)((b * TT + t0) * 2048 + cell * 8));
    half4_t z2 = *(const half4_t*)(zb8 + (unsigned)((b * TT + t1) * 2048 + cell * 8));

    // rolling prefetch offset: first in-loop load is z(2) / z(Lb-3)
    int zoff = (b * TT + (dir ? (Lb - 3) : 2)) * 2048 + cell * 8;
    // rolling store offset + dead-row redirect (row 511 of own seq = guaranteed padding)
    int hoff = (b * TT + t0) * 512 + cell * 2;
    const unsigned deadoff = (unsigned)((b * TT + 511) * 512 + cell * 2);

    __syncthreads();

    const int maxL2 = (maxL + 1) & ~1;

#define LSTM_STEP(RB, ZC, T)                                                      \
    {                                                                             \
        half8_t bf0 = *(const half8_t*)&hb[RB][roff];                             \
        half8_t bf1 = *(const half8_t*)&hb[RB][128 + roff];                       \
        half8_t bf2 = *(const half8_t*)&hb[RB][256 + roff];                       \
        half8_t bf3 = *(const half8_t*)&hb[RB][384 + roff];                       \
        float4_t A0 = (float4_t){0.f, 0.f, 0.f, 0.f};                             \
        float4_t A1 = (float4_t){0.f, 0.f, 0.f, 0.f};                             \
        float4_t A2 = (float4_t){0.f, 0.f, 0.f, 0.f};                             \
        float4_t A3 = (float4_t){0.f, 0.f, 0.f, 0.f};                             \
        A0 = __builtin_amdgcn_mfma_f32_16x16x32_f16(a0[0], bf0, A0, 0, 0, 0);     \
        A1 = __builtin_amdgcn_mfma_f32_16x16x32_f16(a1[0], bf0, A1, 0, 0, 0);     \
        A2 = __builtin_amdgcn_mfma_f32_16x16x32_f16(a2[0], bf0, A2, 0, 0, 0);     \
        A3 = __builtin_amdgcn_mfma_f32_16x16x32_f16(a3[0], bf0, A3, 0, 0, 0);     \
        A0 = __builtin_amdgcn_mfma_f32_16x16x32_f16(a0[1], bf1, A0, 0, 0, 0);     \
        A1 = __builtin_amdgcn_mfma_f32_16x16x32_f16(a1[1], bf1, A1, 0, 0, 0);     \
        A2 = __builtin_amdgcn_mfma_f32_16x16x32_f16(a2[1], bf1, A2, 0, 0, 0);     \
        A3 = __builtin_amdgcn_mfma_f32_16x16x32_f16(a3[1], bf1, A3, 0, 0, 0);     \
        A0 = __builtin_amdgcn_mfma_f32_16x16x32_f16(a0[2], bf2, A0, 0, 0, 0);     \
        A1 = __builtin_amdgcn_mfma_f32_16x16x32_f16(a1[2], bf2, A1, 0, 0, 0);     \
        A2 = __builtin_amdgcn_mfma_f32_16x16x32_f16(a2[2], bf2, A2, 0, 0, 0);     \
        A3 = __builtin_amdgcn_mfma_f32_16x16x32_f16(a3[2], bf2, A3, 0, 0, 0);     \
        A0 = __builtin_amdgcn_mfma_f32_16x16x32_f16(a0[3], bf3, A0, 0, 0, 0);     \
        A1 = __builtin_amdgcn_mfma_f32_16x16x32_f16(a1[3], bf3, A1, 0, 0, 0);     \
        A2 = __builtin_amdgcn_mfma_f32_16x16x32_f16(a2[3], bf3, A2, 0, 0, 0);     \
        A3 = __builtin_amdgcn_mfma_f32_16x16x32_f16(a3[3], bf3, A3, 0, 0, 0);     \
        float g0 = s1 ? A1[0] : (s2 ? A2[0] : (s3 ? A3[0] : A0[0]));              \
        float g1 = s1 ? A1[1] : (s2 ? A2[1] : (s3 ? A3[1] : A0[1]));              \
        float g2 = s1 ? A1[2] : (s2 ? A2[2] : (s3 ? A3[2] : A0[2]));              \
        float g3 = s1 ? A1[3] : (s2 ? A2[3] : (s3 ? A3[3] : A0[3]));              \
        float zi = g0 + (float)ZC[0];                                             \
        float zf = g1 + (float)ZC[1];                                             \
        float zg = g2 + (float)ZC[2];                                             \
        float zo = g3 + (float)ZC[3];                                             \
        ZC = *(const half4_t*)(zb8 + (unsigned)zoff);   /* reload: z(T+2) */      \
        zoff += zdelta;                                                           \
        zoff = zoff < 0 ? 0 : zoff;                                               \
        float si = fast_sigmoid(zi);                                              \
        float sf = fast_sigmoid(zf);                                              \
        float so = fast_sigmoid(zo);                                              \
        float tg = fast_tanh(zg);                                                 \
        c = sf * c + si * tg;                                                     \
        float th = fast_tanh(c);                                                  \
        half_t hh = (half_t)(so * th);                                            \
        hb[RB ^ 1][woff] = hh;                                                    \
        unsigned soff = ((T) < Lb) ? (unsigned)hoff : deadoff;                    \
        *(half_t*)(hob8 + soff) = hh;   /* fire-and-forget */                     \
        hoff += hdelta;                                                           \
        lds_barrier();                                                            \
    }

    for (int t = 0; t < maxL2; t += 2) {
        LSTM_STEP(0, z1, t)
        LSTM_STEP(1, z2, t + 1)
    }
#undef LSTM_STEP
}

// ---------------------------------------------------------------- output projection via MFMA
__global__ __launch_bounds__(256) void k_logits(const half_t* __restrict__ h1,
                                                const half_t* __restrict__ WO,
                                                const float* __restrict__ b_out,
                                                float* __restrict__ logits) {
    int wave = threadIdx.x >> 6;
    int lane = threadIdx.x & 63;
    int m0 = blockIdx.x * 64 + wave * 16;
    int lr = lane & 15;
    int lq = lane >> 4;

    float4_t acc0 = (float4_t){0.f, 0.f, 0.f, 0.f};
    float4_t acc1 = (float4_t){0.f, 0.f, 0.f, 0.f};

    const half_t* Arow = h1 + (size_t)(m0 + lr) * 256 + lq * 8;
    const half_t* Brow = WO + (size_t)lr * 256 + lq * 8;

    #pragma unroll
    for (int k = 0; k < 256; k += 32) {
        half8_t af = *(const half8_t*)(Arow + k);
        half8_t b0 = *(const half8_t*)(Brow + k);
        half8_t b1 = *(const half8_t*)(Brow + 16 * 256 + k);
        acc0 = __builtin_amdgcn_mfma_f32_16x16x32_f16(af, b0, acc0, 0, 0, 0);
        acc1 = __builtin_amdgcn_mfma_f32_16x16x32_f16(af, b1, acc1, 0, 0, 0);
    }
    #pragma unroll
    for (int nt = 0; nt < 2; nt++) {
        int n = nt * 16 + lr;
        float bias = b_out[n];
        #pragma unroll
        for (int i = 0; i < 4; i++) {
            int m = m0 + lq * 4 + i;
            logits[(size_t)m * KK + n] = (nt == 0 ? acc0[i] : acc1[i]) + bias;
        }
    }
}

// ---------------------------------------------------------------- CRF forward + gold (one wave per sequence)
__global__ __launch_bounds__(64) void k_crf(const float* __restrict__ logits,
                                            const float* __restrict__ trans,
                                            const int* __restrict__ y,
                                            const int* __restrict__ lens,
                                            float* __restrict__ out) {
    int b = blockIdx.x;
    int lane = threadIdx.x;
    int k = lane & 31;
    __shared__ float TR[32][33];
    __shared__ __align__(16) float PS[32];

    for (int i = lane; i < 1024; i += 64) TR[i >> 5][i & 31] = trans[i];

    float et[32];
    const float* trow = trans + k * 32;
    #pragma unroll
    for (int j = 0; j < 32; j++) et[j] = __expf(trow[j]);   // exp(-10000) -> 0
    __syncthreads();

    int Lb = lens[b];
    const int* yb = y + b * (TT + 1);
    const float* lgb = logits + (size_t)(b * TT) * KK;

    float g = 0.f;
    for (int t = lane; t < Lb; t += 64) {
        int yt = yb[t], yt1 = yb[t + 1];
        g += lgb[(size_t)t * KK + yt1] + TR[yt1][yt];
    }
    #pragma unroll
    for (int s = 1; s < 64; s <<= 1) g += __shfl_xor(g, s);
    float gold = g + TR[3][yb[Lb]];

    float score = lgb[k] + TR[k][2];   // t=0 analytic (SOS=2)

    for (int t = 1; t < Lb; t++) {
        float lg = lgb[(size_t)t * KK + k];
        float m = __builtin_bit_cast(float, __builtin_amdgcn_readlane(__builtin_bit_cast(int, score), 4));
        float P = __expf(score - m);
        if (lane < 32) PS[k] = P;
        float4 ps[8];
        #pragma unroll
        for (int j = 0; j < 8; j++) ps[j] = *(const float4*)&PS[j * 4];
        const float* psf = (const float*)ps;
        float a0 = 0.f, a1 = 0.f, a2 = 0.f, a3 = 0.f;
        #pragma unroll
        for (int j = 0; j < 8; j++) {
            a0 = fmaf(et[j], psf[j], a0);
            a1 = fmaf(et[j + 8], psf[j + 8], a1);
            a2 = fmaf(et[j + 16], psf[j + 16], a2);
            a3 = fmaf(et[j + 24], psf[j + 24], a3);
        }
        score = lg + m + __logf((a0 + a1) + (a2 + a3));
    }

    float v = score + TR[3][k];
    float m2 = v;
    #pragma unroll
    for (int s = 1; s < 32; s <<= 1) m2 = fmaxf(m2, __shfl_xor(m2, s));
    float e = __expf(v - m2);
    #pragma unroll
    for (int s = 1; s < 32; s <<= 1) e += __shfl_xor(e, s);
    float logZ = m2 + __logf(e);

    if (lane == 0) out[b] = logZ - gold;
}

// ----------------------------------------------------------------
extern "C" void kernel_launch(void* const* d_in, const int* in_sizes, int n_in,
                              void* d_out, int out_size, void* d_ws, size_t ws_size,
                              hipStream_t stream) {
    const int*   x      = (const int*)d_in[0];
    const int*   y      = (const int*)d_in[1];
    const float* embed  = (const float*)d_in[2];
    const float* wi_l0f = (const float*)d_in[3];
    const float* wh_l0f = (const float*)d_in[4];
    const float* b_l0f  = (const float*)d_in[5];
    const float* wi_l0b = (const float*)d_in[6];
    const float* wh_l0b = (const float*)d_in[7];
    const float* b_l0b  = (const float*)d_in[8];
    const float* wi_l1f = (const float*)d_in[9];
    const float* wh_l1f = (const float*)d_in[10];
    const float* b_l1f  = (const float*)d_in[11];
    const float* wi_l1b = (const float*)d_in[12];
    const float* wh_l1b = (const float*)d_in[13];
    const float* b_l1b  = (const float*)d_in[14];
    const float* w_out  = (const float*)d_in[15];
    const float* b_out  = (const float*)d_in[16];
    const float* trans  = (const float*)d_in[17];
    float* out = (float*)d_out;

    char* base = (char*)d_ws;
    size_t off = 0;
    auto take = [&](size_t bytes) -> char* {
        char* r = base + off;
        off = (off + bytes + 255) & ~(size_t)255;
        return r;
    };
    half_t* zA  = (half_t*)take((size_t)MTOT * NWID * 2);  // 64 MiB
    half_t* h0  = (half_t*)take((size_t)MTOT * 256 * 2);   // 16 MiB
    half_t* h1  = (half_t*)take((size_t)MTOT * 256 * 2);   // 16 MiB
    half_t* e16 = (half_t*)take((size_t)MTOT * EE * 2);    // 8 MiB
    float*  lg  = (float*)take((size_t)MTOT * KK * 4);     // 4 MiB
    half_t* W0  = (half_t*)take((size_t)NWID * EE * 2);
    half_t* W1  = (half_t*)take((size_t)NWID * 256 * 2);
    half_t* WO  = (half_t*)take((size_t)KK * 256 * 2);
    int*    lens = (int*)take(BB * 4);

    k_lengths<<<BB, 256, 0, stream>>>(x, lens);
    k_pack<<<256, 256, 0, stream>>>(wi_l0f, wi_l0b, wi_l1f, wi_l1b, w_out, W0, W1, WO);
    k_embed<<<MTOT / 16, 256, 0, stream>>>(x, embed, e16);
    k_gemm<<<dim3(MTOT / 64, 4), 256, 0, stream>>>(e16, W0, b_l0f, b_l0b, zA, 128);
    k_lstm<<<32, 512, 0, stream>>>(zA, wh_l0f, wh_l0b, lens, h0);
    k_gemm<<<dim3(MTOT / 64, 4), 256, 0, stream>>>(h0, W1, b_l1f, b_l1b, zA, 256);
    k_lstm<<<32, 512, 0, stream>>>(zA, wh_l1f, wh_l1b, lens, h1);
    k_logits<<<MTOT / 64, 256, 0, stream>>>(h1, WO, b_out, lg);
    k_crf<<<BB, 64, 0, stream>>>(lg, trans, y, lens, out);
}

// Round 8
// 966.947 us; speedup vs baseline: 2.4001x; 1.0369x over previous
//
#include <hip/hip_runtime.h>

typedef _Float16 half_t;
typedef _Float16 half2_t __attribute__((ext_vector_type(2)));
typedef _Float16 half4_t __attribute__((ext_vector_type(4)));
typedef _Float16 half8_t __attribute__((ext_vector_type(8)));
typedef float float4_t __attribute__((ext_vector_type(4)));

// Problem constants
#define BB 64
#define TT 512
#define EE 128
#define HPP 128
#define KK 32
#define MTOT (BB*TT)     // 32768
#define NWID 1024        // stacked fwd(512)+bwd(512) gate rows, gate-interleaved per dir

// barrier that drains ONLY LDS ops (z prefetch + h global stores stay in flight)
__device__ __forceinline__ void lds_barrier() {
    asm volatile("s_waitcnt lgkmcnt(0)\n\ts_barrier" ::: "memory");
}

__device__ __forceinline__ float fast_sigmoid(float x) {
    return __builtin_amdgcn_rcpf(1.f + __expf(-x));     // v_exp + v_rcp, no div sequence
}
__device__ __forceinline__ float fast_tanh(float x) {
    return 1.f - 2.f * __builtin_amdgcn_rcpf(__expf(2.f * x) + 1.f);
}

// ---------------------------------------------------------------- lengths
__global__ void k_lengths(const int* __restrict__ x, int* __restrict__ lens) {
    __shared__ int cnt;
    if (threadIdx.x == 0) cnt = 0;
    __syncthreads();
    int local = 0;
    for (int t = threadIdx.x; t < TT; t += blockDim.x)
        local += (x[blockIdx.x * TT + t] > 0) ? 1 : 0;
    atomicAdd(&cnt, local);
    __syncthreads();
    if (threadIdx.x == 0) lens[blockIdx.x] = cnt;
}

// ---------------------------------------------------------------- pack weights fp32->fp16
// R8: wi packed into MFMA B-FRAGMENT order: WP[(ntile*KC + kc)*64 + lane][8],
// lane=(lq*16+lr) holds B[n = ntile*16+lr][k = kc*32+lq*8+j] -> each B-frag load
// in k_gemm is base+lane*16B = one contiguous 1KB wave transaction.
__global__ void k_pack(const float* __restrict__ wi0f, const float* __restrict__ wi0b,
                       const float* __restrict__ wi1f, const float* __restrict__ wi1b,
                       const float* __restrict__ w_out,
                       half_t* __restrict__ WP0, half_t* __restrict__ WP1,
                       half_t* __restrict__ WO) {
    int idx = blockIdx.x * blockDim.x + threadIdx.x;
    int stride = gridDim.x * blockDim.x;
    const int n0 = NWID * EE;       // 1024*128, KC0 = 4
    const int n1 = NWID * 256;      // 1024*256, KC1 = 8
    for (int i = idx; i < n0; i += stride) {
        int j8 = i & 7; int ln = (i >> 3) & 63; int rest = i >> 9;
        int kc = rest & 3; int ntg = rest >> 2;
        int lr = ln & 15, lq = ln >> 4;
        int n = ntg * 16 + lr;
        int k = kc * 32 + lq * 8 + j8;
        float v = (n < 512) ? wi0f[n * 128 + k] : wi0b[(n - 512) * 128 + k];
        WP0[i] = (half_t)v;
    }
    for (int i = idx; i < n1; i += stride) {
        int j8 = i & 7; int ln = (i >> 3) & 63; int rest = i >> 9;
        int kc = rest & 7; int ntg = rest >> 3;
        int lr = ln & 15, lq = ln >> 4;
        int n = ntg * 16 + lr;
        int k = kc * 32 + lq * 8 + j8;
        float v = (n < 512) ? wi1f[n * 256 + k] : wi1b[(n - 512) * 256 + k];
        WP1[i] = (half_t)v;
    }
    for (int i = idx; i < KK * 256; i += stride)
        WO[i] = (half_t)w_out[i];
}

// ---------------------------------------------------------------- embedding gather -> fp16
__global__ void k_embed(const int* __restrict__ x, const float* __restrict__ embed,
                        half_t* __restrict__ e16) {
    int bt = blockIdx.x * 16 + (threadIdx.x >> 4);
    int c  = (threadIdx.x & 15) * 8;
    int xi = x[bt];
    const float4* src = (const float4*)(embed + (size_t)xi * EE + c);
    float4 a = src[0], b = src[1];
    half8_t o;
    o[0] = (half_t)a.x; o[1] = (half_t)a.y; o[2] = (half_t)a.z; o[3] = (half_t)a.w;
    o[4] = (half_t)b.x; o[5] = (half_t)b.y; o[6] = (half_t)b.z; o[7] = (half_t)b.w;
    *(half8_t*)(e16 + (size_t)bt * EE + c) = o;
}

// ---------------------------------------------------------------- MFMA GEMM: C[M,1024] = A[M,Kd]*W[1024,Kd]^T + bias
// R8: B from fragment-packed WP (coalesced 1KB wave loads). Epilogue: gate-interleave n.
__global__ __launch_bounds__(256) void k_gemm(const half_t* __restrict__ A,
                                              const half_t* __restrict__ WP,
                                              const float* __restrict__ bias_f,
                                              const float* __restrict__ bias_b,
                                              half_t* __restrict__ C, int Kd) {
    const int KC = Kd >> 5;
    int wave = threadIdx.x >> 6;
    int lane = threadIdx.x & 63;
    int m0 = blockIdx.x * 64 + wave * 16;
    int n0 = blockIdx.y * 256;
    int lr = lane & 15;
    int lq = lane >> 4;

    float4_t acc[16];
    #pragma unroll
    for (int i = 0; i < 16; i++) acc[i] = (float4_t){0.f, 0.f, 0.f, 0.f};

    const half_t* Arow  = A + (size_t)(m0 + lr) * Kd + lq * 8;
    const half_t* Wbase = WP + ((size_t)(n0 >> 4) * KC * 64 + lane) * 8;

    for (int kc = 0; kc < KC; kc++) {
        half8_t af = *(const half8_t*)(Arow + kc * 32);
        #pragma unroll
        for (int nt = 0; nt < 16; nt++) {
            half8_t bf = *(const half8_t*)(Wbase + (((size_t)nt * KC + kc) << 9));
            acc[nt] = __builtin_amdgcn_mfma_f32_16x16x32_f16(af, bf, acc[nt], 0, 0, 0);
        }
    }
    #pragma unroll
    for (int nt = 0; nt < 16; nt++) {
        int n = n0 + nt * 16 + lr;
        int n2 = (n < 512) ? n : n - 512;
        float bias = (n < 512) ? bias_f[n2] : bias_b[n2];
        int np = ((n < 512) ? 0 : 512) + (n2 & 127) * 4 + (n2 >> 7);
        #pragma unroll
        for (int i = 0; i < 4; i++) {
            int m = m0 + lq * 4 + i;
            C[(size_t)m * NWID + np] = (half_t)(acc[nt][i] + bias);
        }
    }
}

// ---------------------------------------------------------------- recurrent LSTM via MFMA, 4 chains per block, 32 blocks
// (frozen from R7: strength-reduced u32 offsets, 2-step unroll, dead-row redirect)
__global__ __launch_bounds__(512, 1) void k_lstm(const half_t* __restrict__ zbuf,
                                                 const float* __restrict__ wh_f,
                                                 const float* __restrict__ wh_b,
                                                 const int* __restrict__ lens,
                                                 half_t* __restrict__ hout) {
    const int grp  = blockIdx.x >> 1;     // 16 seq-groups of 4
    const int dir  = blockIdx.x & 1;
    const int tid  = threadIdx.x;
    const int wv   = tid >> 6;
    const int lane = tid & 63;
    const int q    = lane >> 4;           // k-quad / D-row-quad
    const int col  = lane & 15;           // B column
    const int s    = col & 3;             // seq within group
    const int ii   = col >> 2;            // which M-tile this lane activates
    const int b    = grp * 4 + s;
    const int Lb   = lens[b];
    const int maxL = lens[grp * 4];       // lengths sorted descending
    const float* wh = dir ? wh_b : wh_f;

    __shared__ half_t hb[2][512];   // [buf][ck*128 + (s*4+q)*8 + j]

    // ---- A fragments: Wh rows [wv*64, wv*64+64), gate-interleaved (r = cell*4+gate)
    half8_t a0[4], a1[4], a2[4], a3[4];
    #pragma unroll
    for (int i = 0; i < 4; i++) {
        int r = wv * 64 + i * 16 + col;            // interleaved row; A[m=col][k=q*8+j]
        int orow = (r & 3) * 128 + (r >> 2);       // original wh row = gate*128 + cell
        #pragma unroll
        for (int ck = 0; ck < 4; ck++) {
            const float4* src = (const float4*)(wh + (size_t)orow * 128 + ck * 32 + q * 8);
            float4 f0 = src[0], f1 = src[1];
            half8_t h8;
            h8[0] = (half_t)f0.x; h8[1] = (half_t)f0.y; h8[2] = (half_t)f0.z; h8[3] = (half_t)f0.w;
            h8[4] = (half_t)f1.x; h8[5] = (half_t)f1.y; h8[6] = (half_t)f1.z; h8[7] = (half_t)f1.w;
            if (i == 0) a0[ck] = h8;
            else if (i == 1) a1[ck] = h8;
            else if (i == 2) a2[ck] = h8;
            else a3[ck] = h8;
        }
    }

    hb[0][tid] = (half_t)0.f;   // zero h(0) buffer

    const int cell = wv * 16 + ii * 4 + q;
    const int woff = (cell >> 5) * 128 + (s * 4 + ((cell >> 3) & 3)) * 8 + (cell & 7);
    const int roff = (s * 4 + q) * 8;     // B-frag read offset (+ ck*128)

    const bool s1 = (ii == 1), s2 = (ii == 2), s3 = (ii == 3);

    float c = 0.f;
    const char* zb8  = (const char*)zbuf + dir * 1024;   // + per-lane u32 byte offset
    char*       hob8 = (char*)hout + dir * 256;

    const int zdelta = dir ? -2048 : 2048;
    const int hdelta = dir ? -512 : 512;

    // prologue: load z(0), z(1) directly
    int t0 = dir ? (Lb - 1) : 0;
    int t1 = dir ? (Lb - 2) : 1;          // Lb >= 256, safe
    half4_t z1 = *(const half4_t*)(zb8 + (unsigned)((b * TT + t0) * 2048 + cell * 8));
    half4_t z2 = *(const half4_t*)(zb8 + (unsigned)((b * TT + t1) * 2048 + cell * 8));

    // rolling prefetch offset: first in-loop load is z(2) / z(Lb-3)
    int zoff = (b * TT + (dir ? (Lb - 3) : 2)) * 2048 + cell * 8;
    // rolling store offset + dead-row redirect (row 511 of own seq = guaranteed padding)
    int hoff = (b * TT + t0) * 512 + cell * 2;
    const unsigned deadoff = (unsigned)((b * TT + 511) * 512 + cell * 2);

    __syncthreads();

    const int maxL2 = (maxL + 1) & ~1;

#define LSTM_STEP(RB, ZC, T)                                                      \
    {                                                                             \
        half8_t bf0 = *(const half8_t*)&hb[RB][roff];                             \
        half8_t bf1 = *(const half8_t*)&hb[RB][128 + roff];                       \
        half8_t bf2 = *(const half8_t*)&hb[RB][256 + roff];                       \
        half8_t bf3 = *(const half8_t*)&hb[RB][384 + roff];                       \
        float4_t A0 = (float4_t){0.f, 0.f, 0.f, 0.f};                             \
        float4_t A1 = (float4_t){0.f, 0.f, 0.f, 0.f};                             \
        float4_t A2 = (float4_t){0.f, 0.f, 0.f, 0.f};                             \
        float4_t A3 = (float4_t){0.f, 0.f, 0.f, 0.f};                             \
        A0 = __builtin_amdgcn_mfma_f32_16x16x32_f16(a0[0], bf0, A0, 0, 0, 0);     \
        A1 = __builtin_amdgcn_mfma_f32_16x16x32_f16(a1[0], bf0, A1, 0, 0, 0);     \
        A2 = __builtin_amdgcn_mfma_f32_16x16x32_f16(a2[0], bf0, A2, 0, 0, 0);     \
        A3 = __builtin_amdgcn_mfma_f32_16x16x32_f16(a3[0], bf0, A3, 0, 0, 0);     \
        A0 = __builtin_amdgcn_mfma_f32_16x16x32_f16(a0[1], bf1, A0, 0, 0, 0);     \
        A1 = __builtin_amdgcn_mfma_f32_16x16x32_f16(a1[1], bf1, A1, 0, 0, 0);     \
        A2 = __builtin_amdgcn_mfma_f32_16x16x32_f16(a2[1], bf1, A2, 0, 0, 0);     \
        A3 = __builtin_amdgcn_mfma_f32_16x16x32_f16(a3[1], bf1, A3, 0, 0, 0);     \
        A0 = __builtin_amdgcn_mfma_f32_16x16x32_f16(a0[2], bf2, A0, 0, 0, 0);     \
        A1 = __builtin_amdgcn_mfma_f32_16x16x32_f16(a1[2], bf2, A1, 0, 0, 0);     \
        A2 = __builtin_amdgcn_mfma_f32_16x16x32_f16(a2[2], bf2, A2, 0, 0, 0);     \
        A3 = __builtin_amdgcn_mfma_f32_16x16x32_f16(a3[2], bf2, A3, 0, 0, 0);     \
        A0 = __builtin_amdgcn_mfma_f32_16x16x32_f16(a0[3], bf3, A0, 0, 0, 0);     \
        A1 = __builtin_amdgcn_mfma_f32_16x16x32_f16(a1[3], bf3, A1, 0, 0, 0);     \
        A2 = __builtin_amdgcn_mfma_f32_16x16x32_f16(a2[3], bf3, A2, 0, 0, 0);     \
        A3 = __builtin_amdgcn_mfma_f32_16x16x32_f16(a3[3], bf3, A3, 0, 0, 0);     \
        float g0 = s1 ? A1[0] : (s2 ? A2[0] : (s3 ? A3[0] : A0[0]));              \
        float g1 = s1 ? A1[1] : (s2 ? A2[1] : (s3 ? A3[1] : A0[1]));              \
        float g2 = s1 ? A1[2] : (s2 ? A2[2] : (s3 ? A3[2] : A0[2]));              \
        float g3 = s1 ? A1[3] : (s2 ? A2[3] : (s3 ? A3[3] : A0[3]));              \
        float zi = g0 + (float)ZC[0];                                             \
        float zf = g1 + (float)ZC[1];                                             \
        float zg = g2 + (float)ZC[2];                                             \
        float zo = g3 + (float)ZC[3];                                             \
        ZC = *(const half4_t*)(zb8 + (unsigned)zoff);   /* reload: z(T+2) */      \
        zoff += zdelta;                                                           \
        zoff = zoff < 0 ? 0 : zoff;                                               \
        float si = fast_sigmoid(zi);                                              \
        float sf = fast_sigmoid(zf);                                              \
        float so = fast_sigmoid(zo);                                              \
        float tg = fast_tanh(zg);                                                 \
        c = sf * c + si * tg;                                                     \
        float th = fast_tanh(c);                                                  \
        half_t hh = (half_t)(so * th);                                            \
        hb[RB ^ 1][woff] = hh;                                                    \
        unsigned soff = ((T) < Lb) ? (unsigned)hoff : deadoff;                    \
        *(half_t*)(hob8 + soff) = hh;   /* fire-and-forget */                     \
        hoff += hdelta;                                                           \
        lds_barrier();                                                            \
    }

    for (int t = 0; t < maxL2; t += 2) {
        LSTM_STEP(0, z1, t)
        LSTM_STEP(1, z2, t + 1)
    }
#undef LSTM_STEP
}

// ---------------------------------------------------------------- output projection via MFMA
__global__ __launch_bounds__(256) void k_logits(const half_t* __restrict__ h1,
                                                const half_t* __restrict__ WO,
                                                const float* __restrict__ b_out,
                                                float* __restrict__ logits) {
    int wave = threadIdx.x >> 6;
    int lane = threadIdx.x & 63;
    int m0 = blockIdx.x * 64 + wave * 16;
    int lr = lane & 15;
    int lq = lane >> 4;

    float4_t acc0 = (float4_t){0.f, 0.f, 0.f, 0.f};
    float4_t acc1 = (float4_t){0.f, 0.f, 0.f, 0.f};

    const half_t* Arow = h1 + (size_t)(m0 + lr) * 256 + lq * 8;
    const half_t* Brow = WO + (size_t)lr * 256 + lq * 8;

    #pragma unroll
    for (int k = 0; k < 256; k += 32) {
        half8_t af = *(const half8_t*)(Arow + k);
        half8_t b0 = *(const half8_t*)(Brow + k);
        half8_t b1 = *(const half8_t*)(Brow + 16 * 256 + k);
        acc0 = __builtin_amdgcn_mfma_f32_16x16x32_f16(af, b0, acc0, 0, 0, 0);
        acc1 = __builtin_amdgcn_mfma_f32_16x16x32_f16(af, b1, acc1, 0, 0, 0);
    }
    #pragma unroll
    for (int nt = 0; nt < 2; nt++) {
        int n = nt * 16 + lr;
        float bias = b_out[n];
        #pragma unroll
        for (int i = 0; i < 4; i++) {
            int m = m0 + lq * 4 + i;
            logits[(size_t)m * KK + n] = (nt == 0 ? acc0[i] : acc1[i]) + bias;
        }
    }
}

// ---------------------------------------------------------------- CRF forward + gold (one wave per sequence)
__global__ __launch_bounds__(64) void k_crf(const float* __restrict__ logits,
                                            const float* __restrict__ trans,
                                            const int* __restrict__ y,
                                            const int* __restrict__ lens,
                                            float* __restrict__ out) {
    int b = blockIdx.x;
    int lane = threadIdx.x;
    int k = lane & 31;
    __shared__ float TR[32][33];
    __shared__ __align__(16) float PS[32];

    for (int i = lane; i < 1024; i += 64) TR[i >> 5][i & 31] = trans[i];

    float et[32];
    const float* trow = trans + k * 32;
    #pragma unroll
    for (int j = 0; j < 32; j++) et[j] = __expf(trow[j]);   // exp(-10000) -> 0
    __syncthreads();

    int Lb = lens[b];
    const int* yb = y + b * (TT + 1);
    const float* lgb = logits + (size_t)(b * TT) * KK;

    float g = 0.f;
    for (int t = lane; t < Lb; t += 64) {
        int yt = yb[t], yt1 = yb[t + 1];
        g += lgb[(size_t)t * KK + yt1] + TR[yt1][yt];
    }
    #pragma unroll
    for (int s = 1; s < 64; s <<= 1) g += __shfl_xor(g, s);
    float gold = g + TR[3][yb[Lb]];

    float score = lgb[k] + TR[k][2];   // t=0 analytic (SOS=2)

    for (int t = 1; t < Lb; t++) {
        float lg = lgb[(size_t)t * KK + k];
        float m = __builtin_bit_cast(float, __builtin_amdgcn_readlane(__builtin_bit_cast(int, score), 4));
        float P = __expf(score - m);
        if (lane < 32) PS[k] = P;
        float4 ps[8];
        #pragma unroll
        for (int j = 0; j < 8; j++) ps[j] = *(const float4*)&PS[j * 4];
        const float* psf = (const float*)ps;
        float a0 = 0.f, a1 = 0.f, a2 = 0.f, a3 = 0.f;
        #pragma unroll
        for (int j = 0; j < 8; j++) {
            a0 = fmaf(et[j], psf[j], a0);
            a1 = fmaf(et[j + 8], psf[j + 8], a1);
            a2 = fmaf(et[j + 16], psf[j + 16], a2);
            a3 = fmaf(et[j + 24], psf[j + 24], a3);
        }
        score = lg + m + __logf((a0 + a1) + (a2 + a3));
    }

    float v = score + TR[3][k];
    float m2 = v;
    #pragma unroll
    for (int s = 1; s < 32; s <<= 1) m2 = fmaxf(m2, __shfl_xor(m2, s));
    float e = __expf(v - m2);
    #pragma unroll
    for (int s = 1; s < 32; s <<= 1) e += __shfl_xor(e, s);
    float logZ = m2 + __logf(e);

    if (lane == 0) out[b] = logZ - gold;
}

// ----------------------------------------------------------------
extern "C" void kernel_launch(void* const* d_in, const int* in_sizes, int n_in,
                              void* d_out, int out_size, void* d_ws, size_t ws_size,
                              hipStream_t stream) {
    const int*   x      = (const int*)d_in[0];
    const int*   y      = (const int*)d_in[1];
    const float* embed  = (const float*)d_in[2];
    const float* wi_l0f = (const float*)d_in[3];
    const float* wh_l0f = (const float*)d_in[4];
    const float* b_l0f  = (const float*)d_in[5];
    const float* wi_l0b = (const float*)d_in[6];
    const float* wh_l0b = (const float*)d_in[7];
    const float* b_l0b  = (const float*)d_in[8];
    const float* wi_l1f = (const float*)d_in[9];
    const float* wh_l1f = (const float*)d_in[10];
    const float* b_l1f  = (const float*)d_in[11];
    const float* wi_l1b = (const float*)d_in[12];
    const float* wh_l1b = (const float*)d_in[13];
    const float* b_l1b  = (const float*)d_in[14];
    const float* w_out  = (const float*)d_in[15];
    const float* b_out  = (const float*)d_in[16];
    const float* trans  = (const float*)d_in[17];
    float* out = (float*)d_out;

    char* base = (char*)d_ws;
    size_t off = 0;
    auto take = [&](size_t bytes) -> char* {
        char* r = base + off;
        off = (off + bytes + 255) & ~(size_t)255;
        return r;
    };
    half_t* zA  = (half_t*)take((size_t)MTOT * NWID * 2);  // 64 MiB
    half_t* h0  = (half_t*)take((size_t)MTOT * 256 * 2);   // 16 MiB
    half_t* h1  = (half_t*)take((size_t)MTOT * 256 * 2);   // 16 MiB
    half_t* e16 = (half_t*)take((size_t)MTOT * EE * 2);    // 8 MiB
    float*  lg  = (float*)take((size_t)MTOT * KK * 4);     // 4 MiB
    half_t* WP0 = (half_t*)take((size_t)NWID * EE * 2);
    half_t* WP1 = (half_t*)take((size_t)NWID * 256 * 2);
    half_t* WO  = (half_t*)take((size_t)KK * 256 * 2);
    int*    lens = (int*)take(BB * 4);

    k_lengths<<<BB, 256, 0, stream>>>(x, lens);
    k_pack<<<256, 256, 0, stream>>>(wi_l0f, wi_l0b, wi_l1f, wi_l1b, w_out, WP0, WP1, WO);
    k_embed<<<MTOT / 16, 256, 0, stream>>>(x, embed, e16);
    k_gemm<<<dim3(MTOT / 64, 4), 256, 0, stream>>>(e16, WP0, b_l0f, b_l0b, zA, 128);
    k_lstm<<<32, 512, 0, stream>>>(zA, wh_l0f, wh_l0b, lens, h0);
    k_gemm<<<dim3(MTOT / 64, 4), 256, 0, stream>>>(h0, WP1, b_l1f, b_l1b, zA, 256);
    k_lstm<<<32, 512, 0, stream>>>(zA, wh_l1f, wh_l1b, lens, h1);
    k_logits<<<MTOT / 64, 256, 0, stream>>>(h1, WO, b_out, lg);
    k_crf<<<BB, 64, 0, stream>>>(lg, trans, y, lens, out);
}

// Round 9
// 909.452 us; speedup vs baseline: 2.5518x; 1.0632x over previous
//
#include <hip/hip_runtime.h>

typedef _Float16 half_t;
typedef _Float16 half2_t __attribute__((ext_vector_type(2)));
typedef _Float16 half4_t __attribute__((ext_vector_type(4)));
typedef _Float16 half8_t __attribute__((ext_vector_type(8)));
typedef float float4_t __attribute__((ext_vector_type(4)));

// Problem constants
#define BB 64
#define TT 512
#define EE 128
#define HPP 128
#define KK 32
#define MTOT (BB*TT)     // 32768
#define NWID 1024        // stacked fwd(512)+bwd(512) gate rows, gate-interleaved per dir

// barrier that drains ONLY LDS ops (z prefetch + h global stores stay in flight)
__device__ __forceinline__ void lds_barrier() {
    asm volatile("s_waitcnt lgkmcnt(0)\n\ts_barrier" ::: "memory");
}

__device__ __forceinline__ float fast_sigmoid(float x) {
    return __builtin_amdgcn_rcpf(1.f + __expf(-x));     // v_exp + v_rcp, no div sequence
}
__device__ __forceinline__ float fast_tanh(float x) {
    return 1.f - 2.f * __builtin_amdgcn_rcpf(__expf(2.f * x) + 1.f);
}

// ---------------------------------------------------------------- lengths
__global__ void k_lengths(const int* __restrict__ x, int* __restrict__ lens) {
    __shared__ int cnt;
    if (threadIdx.x == 0) cnt = 0;
    __syncthreads();
    int local = 0;
    for (int t = threadIdx.x; t < TT; t += blockDim.x)
        local += (x[blockIdx.x * TT + t] > 0) ? 1 : 0;
    atomicAdd(&cnt, local);
    __syncthreads();
    if (threadIdx.x == 0) lens[blockIdx.x] = cnt;
}

// ---------------------------------------------------------------- pack weights fp32->fp16
// wi packed into MFMA B-FRAGMENT order: WP[(ntile*KC + kc)*64 + lane][8],
// lane=(lq*16+lr) holds B[n = ntile*16+lr][k = kc*32+lq*8+j].
__global__ void k_pack(const float* __restrict__ wi0f, const float* __restrict__ wi0b,
                       const float* __restrict__ wi1f, const float* __restrict__ wi1b,
                       const float* __restrict__ w_out,
                       half_t* __restrict__ WP0, half_t* __restrict__ WP1,
                       half_t* __restrict__ WO) {
    int idx = blockIdx.x * blockDim.x + threadIdx.x;
    int stride = gridDim.x * blockDim.x;
    const int n0 = NWID * EE;       // 1024*128, KC0 = 4
    const int n1 = NWID * 256;      // 1024*256, KC1 = 8
    for (int i = idx; i < n0; i += stride) {
        int j8 = i & 7; int ln = (i >> 3) & 63; int rest = i >> 9;
        int kc = rest & 3; int ntg = rest >> 2;
        int lr = ln & 15, lq = ln >> 4;
        int n = ntg * 16 + lr;
        int k = kc * 32 + lq * 8 + j8;
        float v = (n < 512) ? wi0f[n * 128 + k] : wi0b[(n - 512) * 128 + k];
        WP0[i] = (half_t)v;
    }
    for (int i = idx; i < n1; i += stride) {
        int j8 = i & 7; int ln = (i >> 3) & 63; int rest = i >> 9;
        int kc = rest & 7; int ntg = rest >> 3;
        int lr = ln & 15, lq = ln >> 4;
        int n = ntg * 16 + lr;
        int k = kc * 32 + lq * 8 + j8;
        float v = (n < 512) ? wi1f[n * 256 + k] : wi1b[(n - 512) * 256 + k];
        WP1[i] = (half_t)v;
    }
    for (int i = idx; i < KK * 256; i += stride)
        WO[i] = (half_t)w_out[i];
}

// ---------------------------------------------------------------- embedding gather -> fp16
__global__ void k_embed(const int* __restrict__ x, const float* __restrict__ embed,
                        half_t* __restrict__ e16) {
    int bt = blockIdx.x * 16 + (threadIdx.x >> 4);
    int c  = (threadIdx.x & 15) * 8;
    int xi = x[bt];
    const float4* src = (const float4*)(embed + (size_t)xi * EE + c);
    float4 a = src[0], b = src[1];
    half8_t o;
    o[0] = (half_t)a.x; o[1] = (half_t)a.y; o[2] = (half_t)a.z; o[3] = (half_t)a.w;
    o[4] = (half_t)b.x; o[5] = (half_t)b.y; o[6] = (half_t)b.z; o[7] = (half_t)b.w;
    *(half8_t*)(e16 + (size_t)bt * EE + c) = o;
}

// ---------------------------------------------------------------- MFMA GEMM: C[M,1024] = A[M,Kd]*W[1024,Kd]^T + bias
// R9: blockIdx.y = dir*2 + cg owns ALL 4 gates of cells [cg*64, cg*64+64) of dir.
// nt = g*4+sub -> n = dir*512 + g*128 + cg*64 + sub*16 + lr. Epilogue assembles
// half4 {g0..g3}+bias per (m,cell): 16 coalesced 8B stores/wave (vs 64 scattered 2B).
__global__ __launch_bounds__(256) void k_gemm(const half_t* __restrict__ A,
                                              const half_t* __restrict__ WP,
                                              const float* __restrict__ bias_f,
                                              const float* __restrict__ bias_b,
                                              half_t* __restrict__ C, int Kd) {
    const int KC = Kd >> 5;
    int wave = threadIdx.x >> 6;
    int lane = threadIdx.x & 63;
    int m0 = blockIdx.x * 64 + wave * 16;
    int dir = blockIdx.y >> 1;
    int cg  = blockIdx.y & 1;
    int lr = lane & 15;
    int lq = lane >> 4;

    float4_t acc[16];
    #pragma unroll
    for (int i = 0; i < 16; i++) acc[i] = (float4_t){0.f, 0.f, 0.f, 0.f};

    const half_t* Arow  = A + (size_t)(m0 + lr) * Kd + lq * 8;
    // ntile(nt = g*4+sub) = dir*32 + g*8 + cg*4 + sub
    const int ntile0 = dir * 32 + cg * 4;
    const half_t* Wbase = WP + ((size_t)ntile0 * KC * 64 + lane) * 8;

    for (int kc = 0; kc < KC; kc++) {
        half8_t af = *(const half8_t*)(Arow + kc * 32);
        #pragma unroll
        for (int nt = 0; nt < 16; nt++) {
            int g = nt >> 2, sub = nt & 3;
            half8_t bf = *(const half8_t*)(Wbase + (((size_t)(g * 8 + sub) * KC + kc) << 9));
            acc[nt] = __builtin_amdgcn_mfma_f32_16x16x32_f16(af, bf, acc[nt], 0, 0, 0);
        }
    }

    const float* bias = dir ? bias_b : bias_f;
    char* Crow = (char*)C + dir * 1024 + (size_t)(cg * 64) * 8;
    #pragma unroll
    for (int sub = 0; sub < 4; sub++) {
        int cbase = cg * 64 + sub * 16 + lr;          // cell index within dir
        float b0 = bias[cbase];                        // gate g row = g*128 + cell
        float b1 = bias[128 + cbase];
        float b2 = bias[256 + cbase];
        float b3 = bias[384 + cbase];
        #pragma unroll
        for (int i = 0; i < 4; i++) {
            int m = m0 + lq * 4 + i;
            half4_t o;
            o[0] = (half_t)(acc[0 * 4 + sub][i] + b0);
            o[1] = (half_t)(acc[1 * 4 + sub][i] + b1);
            o[2] = (half_t)(acc[2 * 4 + sub][i] + b2);
            o[3] = (half_t)(acc[3 * 4 + sub][i] + b3);
            *(half4_t*)(Crow + (size_t)m * 2048 + (sub * 16 + lr) * 8) = o;
        }
    }
}

// ---------------------------------------------------------------- recurrent LSTM via MFMA, 4 chains per block, 32 blocks
// (frozen from R7: strength-reduced u32 offsets, 2-step unroll, dead-row redirect)
__global__ __launch_bounds__(512, 1) void k_lstm(const half_t* __restrict__ zbuf,
                                                 const float* __restrict__ wh_f,
                                                 const float* __restrict__ wh_b,
                                                 const int* __restrict__ lens,
                                                 half_t* __restrict__ hout) {
    const int grp  = blockIdx.x >> 1;     // 16 seq-groups of 4
    const int dir  = blockIdx.x & 1;
    const int tid  = threadIdx.x;
    const int wv   = tid >> 6;
    const int lane = tid & 63;
    const int q    = lane >> 4;           // k-quad / D-row-quad
    const int col  = lane & 15;           // B column
    const int s    = col & 3;             // seq within group
    const int ii   = col >> 2;            // which M-tile this lane activates
    const int b    = grp * 4 + s;
    const int Lb   = lens[b];
    const int maxL = lens[grp * 4];       // lengths sorted descending
    const float* wh = dir ? wh_b : wh_f;

    __shared__ half_t hb[2][512];   // [buf][ck*128 + (s*4+q)*8 + j]

    // ---- A fragments: Wh rows [wv*64, wv*64+64), gate-interleaved (r = cell*4+gate)
    half8_t a0[4], a1[4], a2[4], a3[4];
    #pragma unroll
    for (int i = 0; i < 4; i++) {
        int r = wv * 64 + i * 16 + col;            // interleaved row; A[m=col][k=q*8+j]
        int orow = (r & 3) * 128 + (r >> 2);       // original wh row = gate*128 + cell
        #pragma unroll
        for (int ck = 0; ck < 4; ck++) {
            const float4* src = (const float4*)(wh + (size_t)orow * 128 + ck * 32 + q * 8);
            float4 f0 = src[0], f1 = src[1];
            half8_t h8;
            h8[0] = (half_t)f0.x; h8[1] = (half_t)f0.y; h8[2] = (half_t)f0.z; h8[3] = (half_t)f0.w;
            h8[4] = (half_t)f1.x; h8[5] = (half_t)f1.y; h8[6] = (half_t)f1.z; h8[7] = (half_t)f1.w;
            if (i == 0) a0[ck] = h8;
            else if (i == 1) a1[ck] = h8;
            else if (i == 2) a2[ck] = h8;
            else a3[ck] = h8;
        }
    }

    hb[0][tid] = (half_t)0.f;   // zero h(0) buffer

    const int cell = wv * 16 + ii * 4 + q;
    const int woff = (cell >> 5) * 128 + (s * 4 + ((cell >> 3) & 3)) * 8 + (cell & 7);
    const int roff = (s * 4 + q) * 8;     // B-frag read offset (+ ck*128)

    const bool s1 = (ii == 1), s2 = (ii == 2), s3 = (ii == 3);

    float c = 0.f;
    const char* zb8  = (const char*)zbuf + dir * 1024;   // + per-lane u32 byte offset
    char*       hob8 = (char*)hout + dir * 256;

    const int zdelta = dir ? -2048 : 2048;
    const int hdelta = dir ? -512 : 512;

    // prologue: load z(0), z(1) directly
    int t0 = dir ? (Lb - 1) : 0;
    int t1 = dir ? (Lb - 2) : 1;          // Lb >= 256, safe
    half4_t z1 = *(const half4_t*)(zb8 + (unsigned)((b * TT + t0) * 2048 + cell * 8));
    half4_t z2 = *(const half4_t*)(zb8 + (unsigned)((b * TT + t1) * 2048 + cell * 8));

    // rolling prefetch offset: first in-loop load is z(2) / z(Lb-3)
    int zoff = (b * TT + (dir ? (Lb - 3) : 2)) * 2048 + cell * 8;
    // rolling store offset + dead-row redirect (row 511 of own seq = guaranteed padding)
    int hoff = (b * TT + t0) * 512 + cell * 2;
    const unsigned deadoff = (unsigned)((b * TT + 511) * 512 + cell * 2);

    __syncthreads();

    const int maxL2 = (maxL + 1) & ~1;

#define LSTM_STEP(RB, ZC, T)                                                      \
    {                                                                             \
        half8_t bf0 = *(const half8_t*)&hb[RB][roff];                             \
        half8_t bf1 = *(const half8_t*)&hb[RB][128 + roff];                       \
        half8_t bf2 = *(const half8_t*)&hb[RB][256 + roff];                       \
        half8_t bf3 = *(const half8_t*)&hb[RB][384 + roff];                       \
        float4_t A0 = (float4_t){0.f, 0.f, 0.f, 0.f};                             \
        float4_t A1 = (float4_t){0.f, 0.f, 0.f, 0.f};                             \
        float4_t A2 = (float4_t){0.f, 0.f, 0.f, 0.f};                             \
        float4_t A3 = (float4_t){0.f, 0.f, 0.f, 0.f};                             \
        A0 = __builtin_amdgcn_mfma_f32_16x16x32_f16(a0[0], bf0, A0, 0, 0, 0);     \
        A1 = __builtin_amdgcn_mfma_f32_16x16x32_f16(a1[0], bf0, A1, 0, 0, 0);     \
        A2 = __builtin_amdgcn_mfma_f32_16x16x32_f16(a2[0], bf0, A2, 0, 0, 0);     \
        A3 = __builtin_amdgcn_mfma_f32_16x16x32_f16(a3[0], bf0, A3, 0, 0, 0);     \
        A0 = __builtin_amdgcn_mfma_f32_16x16x32_f16(a0[1], bf1, A0, 0, 0, 0);     \
        A1 = __builtin_amdgcn_mfma_f32_16x16x32_f16(a1[1], bf1, A1, 0, 0, 0);     \
        A2 = __builtin_amdgcn_mfma_f32_16x16x32_f16(a2[1], bf1, A2, 0, 0, 0);     \
        A3 = __builtin_amdgcn_mfma_f32_16x16x32_f16(a3[1], bf1, A3, 0, 0, 0);     \
        A0 = __builtin_amdgcn_mfma_f32_16x16x32_f16(a0[2], bf2, A0, 0, 0, 0);     \
        A1 = __builtin_amdgcn_mfma_f32_16x16x32_f16(a1[2], bf2, A1, 0, 0, 0);     \
        A2 = __builtin_amdgcn_mfma_f32_16x16x32_f16(a2[2], bf2, A2, 0, 0, 0);     \
        A3 = __builtin_amdgcn_mfma_f32_16x16x32_f16(a3[2], bf2, A3, 0, 0, 0);     \
        A0 = __builtin_amdgcn_mfma_f32_16x16x32_f16(a0[3], bf3, A0, 0, 0, 0);     \
        A1 = __builtin_amdgcn_mfma_f32_16x16x32_f16(a1[3], bf3, A1, 0, 0, 0);     \
        A2 = __builtin_amdgcn_mfma_f32_16x16x32_f16(a2[3], bf3, A2, 0, 0, 0);     \
        A3 = __builtin_amdgcn_mfma_f32_16x16x32_f16(a3[3], bf3, A3, 0, 0, 0);     \
        float g0 = s1 ? A1[0] : (s2 ? A2[0] : (s3 ? A3[0] : A0[0]));              \
        float g1 = s1 ? A1[1] : (s2 ? A2[1] : (s3 ? A3[1] : A0[1]));              \
        float g2 = s1 ? A1[2] : (s2 ? A2[2] : (s3 ? A3[2] : A0[2]));              \
        float g3 = s1 ? A1[3] : (s2 ? A2[3] : (s3 ? A3[3] : A0[3]));              \
        float zi = g0 + (float)ZC[0];                                             \
        float zf = g1 + (float)ZC[1];                                             \
        float zg = g2 + (float)ZC[2];                                             \
        float zo = g3 + (float)ZC[3];                                             \
        ZC = *(const half4_t*)(zb8 + (unsigned)zoff);   /* reload: z(T+2) */      \
        zoff += zdelta;                                                           \
        zoff = zoff < 0 ? 0 : zoff;                                               \
        float si = fast_sigmoid(zi);                                              \
        float sf = fast_sigmoid(zf);                                              \
        float so = fast_sigmoid(zo);                                              \
        float tg = fast_tanh(zg);                                                 \
        c = sf * c + si * tg;                                                     \
        float th = fast_tanh(c);                                                  \
        half_t hh = (half_t)(so * th);                                            \
        hb[RB ^ 1][woff] = hh;                                                    \
        unsigned soff = ((T) < Lb) ? (unsigned)hoff : deadoff;                    \
        *(half_t*)(hob8 + soff) = hh;   /* fire-and-forget */                     \
        hoff += hdelta;                                                           \
        lds_barrier();                                                            \
    }

    for (int t = 0; t < maxL2; t += 2) {
        LSTM_STEP(0, z1, t)
        LSTM_STEP(1, z2, t + 1)
    }
#undef LSTM_STEP
}

// ---------------------------------------------------------------- output projection via MFMA
__global__ __launch_bounds__(256) void k_logits(const half_t* __restrict__ h1,
                                                const half_t* __restrict__ WO,
                                                const float* __restrict__ b_out,
                                                float* __restrict__ logits) {
    int wave = threadIdx.x >> 6;
    int lane = threadIdx.x & 63;
    int m0 = blockIdx.x * 64 + wave * 16;
    int lr = lane & 15;
    int lq = lane >> 4;

    float4_t acc0 = (float4_t){0.f, 0.f, 0.f, 0.f};
    float4_t acc1 = (float4_t){0.f, 0.f, 0.f, 0.f};

    const half_t* Arow = h1 + (size_t)(m0 + lr) * 256 + lq * 8;
    const half_t* Brow = WO + (size_t)lr * 256 + lq * 8;

    #pragma unroll
    for (int k = 0; k < 256; k += 32) {
        half8_t af = *(const half8_t*)(Arow + k);
        half8_t b0 = *(const half8_t*)(Brow + k);
        half8_t b1 = *(const half8_t*)(Brow + 16 * 256 + k);
        acc0 = __builtin_amdgcn_mfma_f32_16x16x32_f16(af, b0, acc0, 0, 0, 0);
        acc1 = __builtin_amdgcn_mfma_f32_16x16x32_f16(af, b1, acc1, 0, 0, 0);
    }
    #pragma unroll
    for (int nt = 0; nt < 2; nt++) {
        int n = nt * 16 + lr;
        float bias = b_out[n];
        #pragma unroll
        for (int i = 0; i < 4; i++) {
            int m = m0 + lq * 4 + i;
            logits[(size_t)m * KK + n] = (nt == 0 ? acc0[i] : acc1[i]) + bias;
        }
    }
}

// ---------------------------------------------------------------- CRF forward + gold (one wave per sequence)
__global__ __launch_bounds__(64) void k_crf(const float* __restrict__ logits,
                                            const float* __restrict__ trans,
                                            const int* __restrict__ y,
                                            const int* __restrict__ lens,
                                            float* __restrict__ out) {
    int b = blockIdx.x;
    int lane = threadIdx.x;
    int k = lane & 31;
    __shared__ float TR[32][33];
    __shared__ __align__(16) float PS[32];

    for (int i = lane; i < 1024; i += 64) TR[i >> 5][i & 31] = trans[i];

    float et[32];
    const float* trow = trans + k * 32;
    #pragma unroll
    for (int j = 0; j < 32; j++) et[j] = __expf(trow[j]);   // exp(-10000) -> 0
    __syncthreads();

    int Lb = lens[b];
    const int* yb = y + b * (TT + 1);
    const float* lgb = logits + (size_t)(b * TT) * KK;

    float g = 0.f;
    for (int t = lane; t < Lb; t += 64) {
        int yt = yb[t], yt1 = yb[t + 1];
        g += lgb[(size_t)t * KK + yt1] + TR[yt1][yt];
    }
    #pragma unroll
    for (int s = 1; s < 64; s <<= 1) g += __shfl_xor(g, s);
    float gold = g + TR[3][yb[Lb]];

    float score = lgb[k] + TR[k][2];   // t=0 analytic (SOS=2)

    for (int t = 1; t < Lb; t++) {
        float lg = lgb[(size_t)t * KK + k];
        float m = __builtin_bit_cast(float, __builtin_amdgcn_readlane(__builtin_bit_cast(int, score), 4));
        float P = __expf(score - m);
        if (lane < 32) PS[k] = P;
        float4 ps[8];
        #pragma unroll
        for (int j = 0; j < 8; j++) ps[j] = *(const float4*)&PS[j * 4];
        const float* psf = (const float*)ps;
        float a0 = 0.f, a1 = 0.f, a2 = 0.f, a3 = 0.f;
        #pragma unroll
        for (int j = 0; j < 8; j++) {
            a0 = fmaf(et[j], psf[j], a0);
            a1 = fmaf(et[j + 8], psf[j + 8], a1);
            a2 = fmaf(et[j + 16], psf[j + 16], a2);
            a3 = fmaf(et[j + 24], psf[j + 24], a3);
        }
        score = lg + m + __logf((a0 + a1) + (a2 + a3));
    }

    float v = score + TR[3][k];
    float m2 = v;
    #pragma unroll
    for (int s = 1; s < 32; s <<= 1) m2 = fmaxf(m2, __shfl_xor(m2, s));
    float e = __expf(v - m2);
    #pragma unroll
    for (int s = 1; s < 32; s <<= 1) e += __shfl_xor(e, s);
    float logZ = m2 + __logf(e);

    if (lane == 0) out[b] = logZ - gold;
}

// ----------------------------------------------------------------
extern "C" void kernel_launch(void* const* d_in, const int* in_sizes, int n_in,
                              void* d_out, int out_size, void* d_ws, size_t ws_size,
                              hipStream_t stream) {
    const int*   x      = (const int*)d_in[0];
    const int*   y      = (const int*)d_in[1];
    const float* embed  = (const float*)d_in[2];
    const float* wi_l0f = (const float*)d_in[3];
    const float* wh_l0f = (const float*)d_in[4];
    const float* b_l0f  = (const float*)d_in[5];
    const float* wi_l0b = (const float*)d_in[6];
    const float* wh_l0b = (const float*)d_in[7];
    const float* b_l0b  = (const float*)d_in[8];
    const float* wi_l1f = (const float*)d_in[9];
    const float* wh_l1f = (const float*)d_in[10];
    const float* b_l1f  = (const float*)d_in[11];
    const float* wi_l1b = (const float*)d_in[12];
    const float* wh_l1b = (const float*)d_in[13];
    const float* b_l1b  = (const float*)d_in[14];
    const float* w_out  = (const float*)d_in[15];
    const float* b_out  = (const float*)d_in[16];
    const float* trans  = (const float*)d_in[17];
    float* out = (float*)d_out;

    char* base = (char*)d_ws;
    size_t off = 0;
    auto take = [&](size_t bytes) -> char* {
        char* r = base + off;
        off = (off + bytes + 255) & ~(size_t)255;
        return r;
    };
    half_t* zA  = (half_t*)take((size_t)MTOT * NWID * 2);  // 64 MiB
    half_t* h0  = (half_t*)take((size_t)MTOT * 256 * 2);   // 16 MiB
    half_t* h1  = (half_t*)take((size_t)MTOT * 256 * 2);   // 16 MiB
    half_t* e16 = (half_t*)take((size_t)MTOT * EE * 2);    // 8 MiB
    float*  lg  = (float*)take((size_t)MTOT * KK * 4);     // 4 MiB
    half_t* WP0 = (half_t*)take((size_t)NWID * EE * 2);
    half_t* WP1 = (half_t*)take((size_t)NWID * 256 * 2);
    half_t* WO  = (half_t*)take((size_t)KK * 256 * 2);
    int*    lens = (int*)take(BB * 4);

    k_lengths<<<BB, 256, 0, stream>>>(x, lens);
    k_pack<<<256, 256, 0, stream>>>(wi_l0f, wi_l0b, wi_l1f, wi_l1b, w_out, WP0, WP1, WO);
    k_embed<<<MTOT / 16, 256, 0, stream>>>(x, embed, e16);
    k_gemm<<<dim3(MTOT / 64, 4), 256, 0, stream>>>(e16, WP0, b_l0f, b_l0b, zA, 128);
    k_lstm<<<32, 512, 0, stream>>>(zA, wh_l0f, wh_l0b, lens, h0);
    k_gemm<<<dim3(MTOT / 64, 4), 256, 0, stream>>>(h0, WP1, b_l1f, b_l1b, zA, 256);
    k_lstm<<<32, 512, 0, stream>>>(zA, wh_l1f, wh_l1b, lens, h1);
    k_logits<<<MTOT / 64, 256, 0, stream>>>(h1, WO, b_out, lg);
    k_crf<<<BB, 64, 0, stream>>>(lg, trans, y, lens, out);
}